// Round 1
// baseline (15261.325 us; speedup 1.0000x reference)
//
#include <hip/hip_runtime.h>
#include <math.h>

#define NN 100000
#define NE 300000
#define H 256
#define NT 8
#define NSTEPS 5
#define CHUNK 256
#define NB ((NE + CHUNK - 1) / CHUNK)   // 1172 chunks for the stable sort

// ---------------- embedding gather: h0 = emb[x] ----------------
__global__ void k_embed(const int* __restrict__ x, const float* __restrict__ emb,
                        float* __restrict__ h) {
    int total = NN * (H / 4);
    for (int idx = blockIdx.x * blockDim.x + threadIdx.x; idx < total;
         idx += gridDim.x * blockDim.x) {
        int node = idx >> 6;      // H/4 == 64
        int j4   = idx & 63;
        reinterpret_cast<float4*>(h)[idx] =
            reinterpret_cast<const float4*>(emb + (size_t)x[node] * H)[j4];
    }
}

// ---------------- stable counting sort of edges by type ----------------
__global__ void k_hist(const int* __restrict__ etype, int* __restrict__ hist_tb) {
    __shared__ int lh[NT];
    int b = blockIdx.x;
    if (threadIdx.x < NT) lh[threadIdx.x] = 0;
    __syncthreads();
    int e = b * CHUNK + threadIdx.x;
    if (e < NE) atomicAdd(&lh[etype[e]], 1);
    __syncthreads();
    if (threadIdx.x < NT) hist_tb[threadIdx.x * NB + b] = lh[threadIdx.x];
}

__global__ void k_scan(const int* __restrict__ hist_tb, int* __restrict__ off_tb,
                       int* __restrict__ pstart, int* __restrict__ perm) {
    // single thread; tiny (8*1172 entries)
    int total[NT];
    for (int t = 0; t < NT; t++) {
        int run = 0;
        for (int b = 0; b < NB; b++) {
            off_tb[t * NB + b] = run;
            run += hist_tb[t * NB + b];
        }
        total[t] = run;
    }
    int p = 0;
    for (int t = 0; t < NT; t++) {
        pstart[t] = p;
        int padded = (total[t] + 63) / 64 * 64;
        for (int q = total[t]; q < padded; q++) perm[p + q] = -1;  // pad slots
        p += padded;
    }
    pstart[NT] = p;  // Epad
}

__global__ void k_scatter(const int* __restrict__ etype, const int* __restrict__ off_tb,
                          const int* __restrict__ pstart, int* __restrict__ perm) {
    __shared__ int st[CHUNK];
    int b = blockIdx.x;
    int e = b * CHUNK + threadIdx.x;
    st[threadIdx.x] = (e < NE) ? etype[e] : -1;
    __syncthreads();
    if (e < NE) {
        int t = st[threadIdx.x];
        int r = 0;
        for (int i = 0; i < threadIdx.x; i++) r += (st[i] == t);  // stable in-chunk rank
        perm[pstart[t] + off_tb[t * NB + b] + r] = e;
    }
}

// ---------------- message GEMM: aggr[dst] += h[src] @ W[t] + b[t] ----------------
// 64 edges x 64 cols per block; edges pre-sorted by type (padded segments).
__global__ __launch_bounds__(256) void k_msg(
    const int* __restrict__ perm, const int* __restrict__ pstart,
    const int* __restrict__ ei, const float* __restrict__ hcur,
    const float* __restrict__ Wm, const float* __restrict__ bm,
    float* __restrict__ aggr) {
    int Epad = pstart[NT];
    int e0 = blockIdx.x * 64;
    if (e0 >= Epad) return;
    int t = 0;
    while (t < NT - 1 && e0 >= pstart[t + 1]) t++;
    int j0 = blockIdx.y * 64;

    __shared__ float a[64][17];  // +1 pad: keeps a-reads at <=2-way bank conflict
    __shared__ float b[16][64];
    __shared__ int se[64], de[64];

    int tid = threadIdx.x;
    if (tid < 64) {
        int eid = perm[e0 + tid];
        se[tid] = (eid >= 0) ? ei[eid] : -1;
        de[tid] = (eid >= 0) ? ei[NE + eid] : 0;
    }
    __syncthreads();

    int tr = tid & 15, tc = tid >> 4;
    int lrow = tid >> 2;          // 0..63
    int lc4  = (tid & 3) * 4;     // 0,4,8,12
    const float* wt = Wm + (size_t)t * H * H;
    float acc[4][4] = {};

    for (int k0 = 0; k0 < H; k0 += 16) {
        int s = se[lrow];
        float4 av = make_float4(0.f, 0.f, 0.f, 0.f);
        if (s >= 0)
            av = reinterpret_cast<const float4*>(hcur + (size_t)s * H + k0 + lc4)[0];
        a[lrow][lc4 + 0] = av.x; a[lrow][lc4 + 1] = av.y;
        a[lrow][lc4 + 2] = av.z; a[lrow][lc4 + 3] = av.w;

        int bk = tid >> 4;            // 0..15
        int bj = (tid & 15) * 4;      // 0..60
        float4 bv = reinterpret_cast<const float4*>(wt + (size_t)(k0 + bk) * H + j0 + bj)[0];
        reinterpret_cast<float4*>(&b[bk][bj])[0] = bv;
        __syncthreads();

#pragma unroll
        for (int kk = 0; kk < 16; kk++) {
            float ar[4], br[4];
#pragma unroll
            for (int i = 0; i < 4; i++) ar[i] = a[tr * 4 + i][kk];
#pragma unroll
            for (int j = 0; j < 4; j++) br[j] = b[kk][tc * 4 + j];
#pragma unroll
            for (int i = 0; i < 4; i++)
#pragma unroll
                for (int j = 0; j < 4; j++) acc[i][j] += ar[i] * br[j];
        }
        __syncthreads();
    }

#pragma unroll
    for (int i = 0; i < 4; i++) {
        int row = tr * 4 + i;
        if (se[row] < 0) continue;
        int d = de[row];
#pragma unroll
        for (int j = 0; j < 4; j++) {
            int jj = j0 + tc * 4 + j;
            atomicAdd(&aggr[(size_t)d * H + jj], acc[i][j] + bm[t * H + jj]);
        }
    }
}

// ---------------- fused GRU: h' = GRUCell(aggr, h) ----------------
// Six gate GEMM tiles (i_r,i_z,i_n from aggr; h_r,h_z,h_n from h) accumulated
// in registers, nonlinearity fused in epilogue. 64 nodes x 64 cols per block.
__global__ __launch_bounds__(256) void k_gru(
    const float* __restrict__ aggr, const float* __restrict__ hcur,
    float* __restrict__ hnext,
    const float* __restrict__ wih, const float* __restrict__ whh,
    const float* __restrict__ bih, const float* __restrict__ bhh) {
    int n0 = blockIdx.x * 64;
    int j0 = blockIdx.y * 64;

    __shared__ float aA[64][17];
    __shared__ float aH[64][17];
    __shared__ float bB[6][16][64];

    int tid = threadIdx.x;
    int tr = tid & 15, tc = tid >> 4;
    int lrow = tid >> 2;
    int lc4  = (tid & 3) * 4;
    float acc[6][4][4] = {};

    for (int k0 = 0; k0 < H; k0 += 16) {
        int n = n0 + lrow;
        float4 v0 = make_float4(0.f, 0.f, 0.f, 0.f), v1 = v0;
        if (n < NN) {
            v0 = reinterpret_cast<const float4*>(aggr + (size_t)n * H + k0 + lc4)[0];
            v1 = reinterpret_cast<const float4*>(hcur + (size_t)n * H + k0 + lc4)[0];
        }
        aA[lrow][lc4 + 0] = v0.x; aA[lrow][lc4 + 1] = v0.y;
        aA[lrow][lc4 + 2] = v0.z; aA[lrow][lc4 + 3] = v0.w;
        aH[lrow][lc4 + 0] = v1.x; aH[lrow][lc4 + 1] = v1.y;
        aH[lrow][lc4 + 2] = v1.z; aH[lrow][lc4 + 3] = v1.w;

#pragma unroll
        for (int g = 0; g < 6; g++) {
            const float* wsrc = (g < 3) ? wih : whh;
            int gate = (g < 3) ? g : g - 3;
            float4 wv = reinterpret_cast<const float4*>(
                wsrc + (size_t)(gate * H + j0 + lrow) * H + k0 + lc4)[0];
            bB[g][lc4 + 0][lrow] = wv.x; bB[g][lc4 + 1][lrow] = wv.y;
            bB[g][lc4 + 2][lrow] = wv.z; bB[g][lc4 + 3][lrow] = wv.w;
        }
        __syncthreads();

#pragma unroll
        for (int kk = 0; kk < 16; kk++) {
            float ag[4], ah[4];
#pragma unroll
            for (int i = 0; i < 4; i++) {
                ag[i] = aA[tr * 4 + i][kk];
                ah[i] = aH[tr * 4 + i][kk];
            }
#pragma unroll
            for (int g = 0; g < 6; g++) {
                float bb[4];
#pragma unroll
                for (int j = 0; j < 4; j++) bb[j] = bB[g][kk][tc * 4 + j];
                if (g < 3) {
#pragma unroll
                    for (int i = 0; i < 4; i++)
#pragma unroll
                        for (int j = 0; j < 4; j++) acc[g][i][j] += ag[i] * bb[j];
                } else {
#pragma unroll
                    for (int i = 0; i < 4; i++)
#pragma unroll
                        for (int j = 0; j < 4; j++) acc[g][i][j] += ah[i] * bb[j];
                }
            }
        }
        __syncthreads();
    }

#pragma unroll
    for (int i = 0; i < 4; i++) {
        int n = n0 + tr * 4 + i;
        if (n >= NN) continue;
#pragma unroll
        for (int j = 0; j < 4; j++) {
            int jj = j0 + tc * 4 + j;
            float ir  = acc[0][i][j] + bih[jj];
            float iz  = acc[1][i][j] + bih[H + jj];
            float in_ = acc[2][i][j] + bih[2 * H + jj];
            float hr  = acc[3][i][j] + bhh[jj];
            float hz  = acc[4][i][j] + bhh[H + jj];
            float hn  = acc[5][i][j] + bhh[2 * H + jj];
            float r = 1.f / (1.f + expf(-(ir + hr)));
            float z = 1.f / (1.f + expf(-(iz + hz)));
            float nv = tanhf(in_ + r * hn);
            float ho = hcur[(size_t)n * H + jj];
            hnext[(size_t)n * H + jj] = (1.f - z) * nv + z * ho;
        }
    }
}

extern "C" void kernel_launch(void* const* d_in, const int* in_sizes, int n_in,
                              void* d_out, int out_size, void* d_ws, size_t ws_size,
                              hipStream_t stream) {
    const int*   x     = (const int*)d_in[0];
    const int*   ei    = (const int*)d_in[1];   // [2, NE]
    const int*   etype = (const int*)d_in[2];
    const float* emb   = (const float*)d_in[3];
    const float* Wm    = (const float*)d_in[4]; // [NT, H, H]
    const float* bm    = (const float*)d_in[5]; // [NT, H]
    const float* wih   = (const float*)d_in[6]; // [3H, H]
    const float* whh   = (const float*)d_in[7]; // [3H, H]
    const float* bih   = (const float*)d_in[8];
    const float* bhh   = (const float*)d_in[9];

    float* out = (float*)d_out;

    // workspace layout
    float* ws_h = (float*)d_ws;                       // [NN, H]
    float* aggr = ws_h + (size_t)NN * H;              // [NN, H]
    int* hist_tb = (int*)(aggr + (size_t)NN * H);     // [NT, NB]
    int* off_tb  = hist_tb + NT * NB;                 // [NT, NB]
    int* pstart  = off_tb + NT * NB;                  // [NT+1]
    int* perm    = pstart + 16;                       // [NE + NT*64]

    // h0 = emb[x]  (buffer A = ws_h; 5 steps -> final lands in d_out)
    k_embed<<<2048, 256, 0, stream>>>(x, emb, ws_h);

    // deterministic stable counting sort of edges by type
    k_hist<<<NB, CHUNK, 0, stream>>>(etype, hist_tb);
    k_scan<<<1, 1, 0, stream>>>(hist_tb, off_tb, pstart, perm);
    k_scatter<<<NB, CHUNK, 0, stream>>>(etype, off_tb, pstart, perm);

    const int MSG_BX = (NE + NT * 64 + 63) / 64;      // covers max padded length
    const int GRU_BX = (NN + 63) / 64;

    float* hcur = ws_h;
    float* hnxt = out;
    for (int s = 0; s < NSTEPS; s++) {
        hipMemsetAsync(aggr, 0, (size_t)NN * H * sizeof(float), stream);
        k_msg<<<dim3(MSG_BX, 4), 256, 0, stream>>>(perm, pstart, ei, hcur, Wm, bm, aggr);
        k_gru<<<dim3(GRU_BX, 4), 256, 0, stream>>>(aggr, hcur, hnxt, wih, whh, bih, bhh);
        float* tmp = hcur; hcur = hnxt; hnxt = tmp;
    }
    // after 5 swaps, final h is in d_out (ws_h -> out -> ws_h -> out -> ws_h -> out)
}

// Round 2
// 5093.356 us; speedup vs baseline: 2.9963x; 2.9963x over previous
//
#include <hip/hip_runtime.h>
#include <math.h>

#define NN 100000
#define NE 300000
#define H 256
#define NT 8
#define NSTEPS 5
#define CHUNK 256
#define NB ((NE + CHUNK - 1) / CHUNK)

typedef __attribute__((ext_vector_type(8))) short bf16x8;
typedef __attribute__((ext_vector_type(4))) float f32x4;

// RNE float -> bf16 bits
static __device__ __forceinline__ short f2bf(float f) {
    union { float f; unsigned u; } v; v.f = f;
    unsigned r = (v.u + 0x7FFFu + ((v.u >> 16) & 1u)) >> 16;
    return (short)r;
}

// ---------------- embedding gather: h0 = emb[x] (fp32) ----------------
__global__ void k_embed(const int* __restrict__ x, const float* __restrict__ emb,
                        float* __restrict__ h) {
    int total = NN * (H / 4);
    for (int idx = blockIdx.x * blockDim.x + threadIdx.x; idx < total;
         idx += gridDim.x * blockDim.x) {
        int node = idx >> 6;
        int j4   = idx & 63;
        reinterpret_cast<float4*>(h)[idx] =
            reinterpret_cast<const float4*>(emb + (size_t)x[node] * H)[j4];
    }
}

// ---------------- weight prep: bf16 copies (W_msg transposed) ----------------
__global__ void k_prep(const float* __restrict__ wih, const float* __restrict__ whh,
                       const float* __restrict__ Wm,
                       short* __restrict__ wihb, short* __restrict__ whhb,
                       short* __restrict__ WmT) {
    int n1 = 3 * H * H;             // 196608
    int n2 = NT * H * H;            // 524288
    for (int i = blockIdx.x * blockDim.x + threadIdx.x; i < n1 + n2;
         i += gridDim.x * blockDim.x) {
        if (i < n1) {
            wihb[i] = f2bf(wih[i]);
            whhb[i] = f2bf(whh[i]);
        } else {
            int idx = i - n1;
            int t = idx >> 16, rem = idx & 65535;
            int j = rem >> 8, k = rem & 255;
            // WmT[t][j][k] = Wm[t][k][j]
            WmT[idx] = f2bf(Wm[(size_t)t * H * H + (size_t)k * H + j]);
        }
    }
}

// ---------------- stable counting sort of edges by type ----------------
__global__ void k_hist(const int* __restrict__ etype, int* __restrict__ hist_tb) {
    __shared__ int lh[NT];
    int b = blockIdx.x;
    if (threadIdx.x < NT) lh[threadIdx.x] = 0;
    __syncthreads();
    int e = b * CHUNK + threadIdx.x;
    if (e < NE) atomicAdd(&lh[etype[e]], 1);
    __syncthreads();
    if (threadIdx.x < NT) hist_tb[threadIdx.x * NB + b] = lh[threadIdx.x];
}

__global__ void k_scan(const int* __restrict__ hist_tb, int* __restrict__ off_tb,
                       int* __restrict__ pstart, int* __restrict__ perm) {
    __shared__ int total[NT];
    int t = threadIdx.x;
    if (t < NT) {
        int run = 0;
        for (int b = 0; b < NB; b++) {
            off_tb[t * NB + b] = run;
            run += hist_tb[t * NB + b];
        }
        total[t] = run;
    }
    __syncthreads();
    if (t == 0) {
        int p = 0;
        for (int tt = 0; tt < NT; tt++) {
            pstart[tt] = p;
            int padded = (total[tt] + 63) / 64 * 64;
            for (int q = total[tt]; q < padded; q++) perm[p + q] = -1;
            p += padded;
        }
        pstart[NT] = p;
    }
}

__global__ void k_scatter(const int* __restrict__ etype, const int* __restrict__ off_tb,
                          const int* __restrict__ pstart, int* __restrict__ perm) {
    __shared__ int st[CHUNK];
    int b = blockIdx.x;
    int e = b * CHUNK + threadIdx.x;
    st[threadIdx.x] = (e < NE) ? etype[e] : -1;
    __syncthreads();
    if (e < NE) {
        int t = st[threadIdx.x];
        int r = 0;
        for (int i = 0; i < threadIdx.x; i++) r += (st[i] == t);
        perm[pstart[t] + off_tb[t * NB + b] + r] = e;
    }
}

// ---------------- message GEMM (MFMA): aggr[dst] += h[src] @ W[t] + b[t] ----
// 64 edges x 64 cols per block; 4 waves each compute a 32x32 tile.
__global__ __launch_bounds__(256) void k_msg(
    const int* __restrict__ perm, const int* __restrict__ pstart,
    const int* __restrict__ ei, const float* __restrict__ hcur,
    const short* __restrict__ WmT, const float* __restrict__ bm,
    float* __restrict__ aggr) {
    int Epad = pstart[NT];
    int e0 = blockIdx.x * 64;
    if (e0 >= Epad) return;
    int t = 0;
    while (t < NT - 1 && e0 >= pstart[t + 1]) t++;
    int j0 = blockIdx.y * 64;

    __shared__ int se[64], de[64];
    int tid = threadIdx.x;
    if (tid < 64) {
        int eid = perm[e0 + tid];
        se[tid] = (eid >= 0) ? ei[eid] : -1;
        de[tid] = (eid >= 0) ? ei[NE + eid] : 0;
    }
    __syncthreads();

    int wid = tid >> 6, lane = tid & 63;
    int wr = (wid & 1) * 32, wc = (wid >> 1) * 32;
    int lr = lane & 15, lg = lane >> 4;

    const short* wt = WmT + (size_t)t * H * H;   // [j][k]
    f32x4 acc[2][2] = {};

    for (int k0 = 0; k0 < H; k0 += 32) {
        bf16x8 fa[2];
#pragma unroll
        for (int rh = 0; rh < 2; rh++) {
            int s = se[wr + rh * 16 + lr];
            bf16x8 v = {};
            if (s >= 0) {
                const float* p = hcur + (size_t)s * H + k0 + lg * 8;
                float4 u0 = *(const float4*)p;
                float4 u1 = *(const float4*)(p + 4);
                v[0] = f2bf(u0.x); v[1] = f2bf(u0.y); v[2] = f2bf(u0.z); v[3] = f2bf(u0.w);
                v[4] = f2bf(u1.x); v[5] = f2bf(u1.y); v[6] = f2bf(u1.z); v[7] = f2bf(u1.w);
            }
            fa[rh] = v;
        }
        bf16x8 fb[2];
#pragma unroll
        for (int ch = 0; ch < 2; ch++) {
            int c = j0 + wc + ch * 16 + lr;
            fb[ch] = *(const bf16x8*)(wt + (size_t)c * H + k0 + lg * 8);
        }
#pragma unroll
        for (int rh = 0; rh < 2; rh++)
#pragma unroll
            for (int ch = 0; ch < 2; ch++)
                acc[rh][ch] = __builtin_amdgcn_mfma_f32_16x16x32_bf16(
                    fa[rh], fb[ch], acc[rh][ch], 0, 0, 0);
    }

#pragma unroll
    for (int rh = 0; rh < 2; rh++) {
#pragma unroll
        for (int reg = 0; reg < 4; reg++) {
            int row = wr + rh * 16 + lg * 4 + reg;
            int s = se[row];
            if (s < 0) continue;
            int d = de[row];
#pragma unroll
            for (int ch = 0; ch < 2; ch++) {
                int jj = j0 + wc + ch * 16 + lr;
                atomicAdd(&aggr[(size_t)d * H + jj], acc[rh][ch][reg] + bm[t * H + jj]);
            }
        }
    }
}

// ---------------- fused GRU (MFMA): h' = GRUCell(aggr, h) ----------------
__global__ __launch_bounds__(256) void k_gru(
    const float* __restrict__ aggr, const float* __restrict__ hcur,
    float* __restrict__ hnext,
    const short* __restrict__ wihb, const short* __restrict__ whhb,
    const float* __restrict__ bih, const float* __restrict__ bhh) {
    int n0 = blockIdx.x * 64;
    int j0 = blockIdx.y * 64;
    int tid = threadIdx.x;
    int wid = tid >> 6, lane = tid & 63;
    int wr = (wid & 1) * 32, wc = (wid >> 1) * 32;
    int lr = lane & 15, lg = lane >> 4;

    f32x4 acc[6][2][2] = {};

    for (int k0 = 0; k0 < H; k0 += 32) {
        bf16x8 fa[2], fh[2];
#pragma unroll
        for (int rh = 0; rh < 2; rh++) {
            int n = n0 + wr + rh * 16 + lr;
            bf16x8 va = {}, vh = {};
            if (n < NN) {
                const float* pa = aggr + (size_t)n * H + k0 + lg * 8;
                const float* ph = hcur + (size_t)n * H + k0 + lg * 8;
                float4 a0 = *(const float4*)pa, a1 = *(const float4*)(pa + 4);
                float4 h0 = *(const float4*)ph, h1 = *(const float4*)(ph + 4);
                va[0] = f2bf(a0.x); va[1] = f2bf(a0.y); va[2] = f2bf(a0.z); va[3] = f2bf(a0.w);
                va[4] = f2bf(a1.x); va[5] = f2bf(a1.y); va[6] = f2bf(a1.z); va[7] = f2bf(a1.w);
                vh[0] = f2bf(h0.x); vh[1] = f2bf(h0.y); vh[2] = f2bf(h0.z); vh[3] = f2bf(h0.w);
                vh[4] = f2bf(h1.x); vh[5] = f2bf(h1.y); vh[6] = f2bf(h1.z); vh[7] = f2bf(h1.w);
            }
            fa[rh] = va; fh[rh] = vh;
        }
#pragma unroll
        for (int g = 0; g < 6; g++) {
            const short* wb = ((g < 3) ? wihb : whhb) + (size_t)(g % 3) * H * H;
            bf16x8 fb[2];
#pragma unroll
            for (int ch = 0; ch < 2; ch++) {
                int c = j0 + wc + ch * 16 + lr;
                fb[ch] = *(const bf16x8*)(wb + (size_t)c * H + k0 + lg * 8);
            }
#pragma unroll
            for (int rh = 0; rh < 2; rh++)
#pragma unroll
                for (int ch = 0; ch < 2; ch++)
                    acc[g][rh][ch] = __builtin_amdgcn_mfma_f32_16x16x32_bf16(
                        (g < 3) ? fa[rh] : fh[rh], fb[ch], acc[g][rh][ch], 0, 0, 0);
        }
    }

#pragma unroll
    for (int rh = 0; rh < 2; rh++) {
#pragma unroll
        for (int reg = 0; reg < 4; reg++) {
            int n = n0 + wr + rh * 16 + lg * 4 + reg;
            if (n >= NN) continue;
#pragma unroll
            for (int ch = 0; ch < 2; ch++) {
                int jj = j0 + wc + ch * 16 + lr;
                float ir  = acc[0][rh][ch][reg] + bih[jj];
                float iz  = acc[1][rh][ch][reg] + bih[H + jj];
                float in_ = acc[2][rh][ch][reg] + bih[2 * H + jj];
                float hr  = acc[3][rh][ch][reg] + bhh[jj];
                float hz  = acc[4][rh][ch][reg] + bhh[H + jj];
                float hn  = acc[5][rh][ch][reg] + bhh[2 * H + jj];
                float r = 1.f / (1.f + expf(-(ir + hr)));
                float z = 1.f / (1.f + expf(-(iz + hz)));
                float nv = tanhf(in_ + r * hn);
                float ho = hcur[(size_t)n * H + jj];
                hnext[(size_t)n * H + jj] = (1.f - z) * nv + z * ho;
            }
        }
    }
}

extern "C" void kernel_launch(void* const* d_in, const int* in_sizes, int n_in,
                              void* d_out, int out_size, void* d_ws, size_t ws_size,
                              hipStream_t stream) {
    const int*   x     = (const int*)d_in[0];
    const int*   ei    = (const int*)d_in[1];
    const int*   etype = (const int*)d_in[2];
    const float* emb   = (const float*)d_in[3];
    const float* Wm    = (const float*)d_in[4];
    const float* bm    = (const float*)d_in[5];
    const float* wih   = (const float*)d_in[6];
    const float* whh   = (const float*)d_in[7];
    const float* bih   = (const float*)d_in[8];
    const float* bhh   = (const float*)d_in[9];

    float* out = (float*)d_out;

    // workspace layout
    float* ws_h = (float*)d_ws;                        // [NN, H] fp32
    float* aggr = ws_h + (size_t)NN * H;               // [NN, H] fp32
    short* wihb = (short*)(aggr + (size_t)NN * H);     // [3H, H] bf16
    short* whhb = wihb + 3 * H * H;                    // [3H, H] bf16
    short* WmT  = whhb + 3 * H * H;                    // [NT, H, H] bf16 (transposed)
    int* hist_tb = (int*)(WmT + NT * H * H);           // [NT, NB]
    int* off_tb  = hist_tb + NT * NB;
    int* pstart  = off_tb + NT * NB;                   // [NT+1]
    int* perm    = pstart + 16;                        // [NE + NT*64]

    k_embed<<<2048, 256, 0, stream>>>(x, emb, ws_h);
    k_prep<<<720, 256, 0, stream>>>(wih, whh, Wm, wihb, whhb, WmT);

    k_hist<<<NB, CHUNK, 0, stream>>>(etype, hist_tb);
    k_scan<<<1, 64, 0, stream>>>(hist_tb, off_tb, pstart, perm);
    k_scatter<<<NB, CHUNK, 0, stream>>>(etype, off_tb, pstart, perm);

    const int MSG_BX = (NE + NT * 64 + 63) / 64;
    const int GRU_BX = (NN + 63) / 64;

    float* hcur = ws_h;
    float* hnxt = out;
    for (int s = 0; s < NSTEPS; s++) {
        hipMemsetAsync(aggr, 0, (size_t)NN * H * sizeof(float), stream);
        k_msg<<<dim3(MSG_BX, 4), 256, 0, stream>>>(perm, pstart, ei, hcur, WmT, bm, aggr);
        k_gru<<<dim3(GRU_BX, 4), 256, 0, stream>>>(aggr, hcur, hnxt, wihb, whhb, bih, bhh);
        float* tmp = hcur; hcur = hnxt; hnxt = tmp;
    }
}

// Round 3
// 4363.120 us; speedup vs baseline: 3.4978x; 1.1674x over previous
//
#include <hip/hip_runtime.h>
#include <math.h>

#define NN 100000
#define NE 300000
#define H 256
#define NT 8
#define NSTEPS 5
#define CHUNK 256
#define NB ((NE + CHUNK - 1) / CHUNK)
#define RS 264   // LDS row stride in shorts: 132 dwords == 4 mod 32 -> b128 reads 2-way (free)

typedef __attribute__((ext_vector_type(8))) short bf16x8;
typedef __attribute__((ext_vector_type(4))) float f32x4;

// RNE float -> bf16 bits
static __device__ __forceinline__ short f2bf(float f) {
    union { float f; unsigned u; } v; v.f = f;
    unsigned r = (v.u + 0x7FFFu + ((v.u >> 16) & 1u)) >> 16;
    return (short)r;
}

// ---------------- embedding gather: h0 = emb[x] (fp32) ----------------
__global__ void k_embed(const int* __restrict__ x, const float* __restrict__ emb,
                        float* __restrict__ h) {
    int total = NN * (H / 4);
    for (int idx = blockIdx.x * blockDim.x + threadIdx.x; idx < total;
         idx += gridDim.x * blockDim.x) {
        int node = idx >> 6;
        int j4   = idx & 63;
        reinterpret_cast<float4*>(h)[idx] =
            reinterpret_cast<const float4*>(emb + (size_t)x[node] * H)[j4];
    }
}

// ---------------- weight prep: bf16 copies (W_msg transposed) ----------------
__global__ void k_prep(const float* __restrict__ wih, const float* __restrict__ whh,
                       const float* __restrict__ Wm,
                       short* __restrict__ wihb, short* __restrict__ whhb,
                       short* __restrict__ WmT) {
    int n1 = 3 * H * H;
    int n2 = NT * H * H;
    for (int i = blockIdx.x * blockDim.x + threadIdx.x; i < n1 + n2;
         i += gridDim.x * blockDim.x) {
        if (i < n1) {
            wihb[i] = f2bf(wih[i]);
            whhb[i] = f2bf(whh[i]);
        } else {
            int idx = i - n1;
            int t = idx >> 16, rem = idx & 65535;
            int j = rem >> 8, k = rem & 255;
            WmT[idx] = f2bf(Wm[(size_t)t * H * H + (size_t)k * H + j]);
        }
    }
}

// ---------------- stable counting sort of edges by type ----------------
__global__ void k_hist(const int* __restrict__ etype, int* __restrict__ hist_tb) {
    __shared__ int lh[NT];
    int b = blockIdx.x;
    if (threadIdx.x < NT) lh[threadIdx.x] = 0;
    __syncthreads();
    int e = b * CHUNK + threadIdx.x;
    if (e < NE) atomicAdd(&lh[etype[e]], 1);
    __syncthreads();
    if (threadIdx.x < NT) hist_tb[threadIdx.x * NB + b] = lh[threadIdx.x];
}

__global__ void k_scan(const int* __restrict__ hist_tb, int* __restrict__ off_tb,
                       int* __restrict__ pstart, int* __restrict__ perm) {
    __shared__ int total[NT];
    int t = threadIdx.x;
    if (t < NT) {
        int run = 0;
        for (int b = 0; b < NB; b++) {
            off_tb[t * NB + b] = run;
            run += hist_tb[t * NB + b];
        }
        total[t] = run;
    }
    __syncthreads();
    if (t == 0) {
        int p = 0;
        for (int tt = 0; tt < NT; tt++) {
            pstart[tt] = p;
            int padded = (total[tt] + 63) / 64 * 64;
            for (int q = total[tt]; q < padded; q++) perm[p + q] = -1;
            p += padded;
        }
        pstart[NT] = p;
    }
}

__global__ void k_scatter(const int* __restrict__ etype, const int* __restrict__ off_tb,
                          const int* __restrict__ pstart, int* __restrict__ perm) {
    __shared__ int st[CHUNK];
    int b = blockIdx.x;
    int e = b * CHUNK + threadIdx.x;
    st[threadIdx.x] = (e < NE) ? etype[e] : -1;
    __syncthreads();
    if (e < NE) {
        int t = st[threadIdx.x];
        int r = 0;
        for (int i = 0; i < threadIdx.x; i++) r += (st[i] == t);
        perm[pstart[t] + off_tb[t * NB + b] + r] = e;
    }
}

// ---------------- message GEMM (MFMA): aggr[dst] += h[src] @ W[t] + b[t] ----
// Block: 64 edges x 256 cols, 512 threads (8 waves x 32-col slice).
// h[src] gathered ONCE into LDS (bf16).
__global__ __launch_bounds__(512) void k_msg(
    const int* __restrict__ perm, const int* __restrict__ pstart,
    const int* __restrict__ ei, const float* __restrict__ hcur,
    const short* __restrict__ WmT, const float* __restrict__ bm,
    float* __restrict__ aggr) {
    int Epad = pstart[NT];
    int e0 = blockIdx.x * 64;
    if (e0 >= Epad) return;
    int t = 0;
    while (t < NT - 1 && e0 >= pstart[t + 1]) t++;

    __shared__ short sA[64][RS];
    __shared__ int se[64], de[64];

    int tid = threadIdx.x;
    if (tid < 64) {
        int eid = perm[e0 + tid];
        se[tid] = (eid >= 0) ? ei[eid] : -1;
        de[tid] = (eid >= 0) ? ei[NE + eid] : 0;
    }
    __syncthreads();

    // stage h[src] tile -> LDS bf16: thread t handles row t>>3, 32 cols
    {
        int r = tid >> 3, c0 = (tid & 7) * 32;
        int s = se[r];
        short tmp[32];
        if (s >= 0) {
            const float* p = hcur + (size_t)s * H + c0;
#pragma unroll
            for (int i = 0; i < 32; i++) tmp[i] = f2bf(p[i]);
        } else {
#pragma unroll
            for (int i = 0; i < 32; i++) tmp[i] = 0;
        }
#pragma unroll
        for (int i = 0; i < 4; i++)
            *(bf16x8*)&sA[r][c0 + i * 8] = *(bf16x8*)&tmp[i * 8];
    }
    __syncthreads();

    int wid = tid >> 6, lane = tid & 63;
    int jw = wid * 32;
    int lr = lane & 15, lg = lane >> 4;

    const short* wt = WmT + (size_t)t * H * H;   // [j][k]
    f32x4 acc[4][2] = {};

    for (int k0 = 0; k0 < H; k0 += 32) {
        bf16x8 fb[2];
#pragma unroll
        for (int ch = 0; ch < 2; ch++) {
            int c = jw + ch * 16 + lr;
            fb[ch] = *(const bf16x8*)(wt + (size_t)c * H + k0 + lg * 8);
        }
#pragma unroll
        for (int rh = 0; rh < 4; rh++) {
            bf16x8 fa = *(const bf16x8*)&sA[rh * 16 + lr][k0 + lg * 8];
#pragma unroll
            for (int ch = 0; ch < 2; ch++)
                acc[rh][ch] = __builtin_amdgcn_mfma_f32_16x16x32_bf16(
                    fa, fb[ch], acc[rh][ch], 0, 0, 0);
        }
    }

#pragma unroll
    for (int rh = 0; rh < 4; rh++) {
#pragma unroll
        for (int reg = 0; reg < 4; reg++) {
            int row = rh * 16 + lg * 4 + reg;
            int s = se[row];
            if (s < 0) continue;
            int d = de[row];
#pragma unroll
            for (int ch = 0; ch < 2; ch++) {
                int jj = jw + ch * 16 + lr;
                atomicAdd(&aggr[(size_t)d * H + jj], acc[rh][ch][reg] + bm[t * H + jj]);
            }
        }
    }
}

// ---------------- fused GRU (MFMA): h' = GRUCell(aggr, h) ----------------
// Block: 16 nodes x 256 cols, 512 threads (8 waves x 32-col slice).
// aggr+hcur rows staged ONCE into LDS (bf16) -> each row fetched once from HBM.
__global__ __launch_bounds__(512) void k_gru(
    const float* __restrict__ aggr, const float* __restrict__ hcur,
    float* __restrict__ hnext,
    const short* __restrict__ wihb, const short* __restrict__ whhb,
    const float* __restrict__ bih, const float* __restrict__ bhh) {
    int n0 = blockIdx.x * 16;     // NN == 16*6250 exactly, no tail
    int tid = threadIdx.x;

    __shared__ short sA[16][RS];
    __shared__ short sH[16][RS];

    // stage: threads 0..255 -> aggr, 256..511 -> hcur; thread handles 16 cols of one row
    {
        int which = tid >> 8;            // 0: aggr, 1: hcur
        int t2 = tid & 255;
        int r = t2 >> 4, c0 = (t2 & 15) * 16;
        const float* src = (which ? hcur : aggr) + (size_t)(n0 + r) * H + c0;
        short tmp[16];
#pragma unroll
        for (int i = 0; i < 16; i++) tmp[i] = f2bf(src[i]);
        short* dst = which ? &sH[r][c0] : &sA[r][c0];
        *(bf16x8*)dst = *(bf16x8*)&tmp[0];
        *(bf16x8*)(dst + 8) = *(bf16x8*)&tmp[8];
    }
    __syncthreads();

    int wid = tid >> 6, lane = tid & 63;
    int jw = wid * 32;
    int lr = lane & 15, lg = lane >> 4;

    f32x4 acc[6][2] = {};

    for (int k0 = 0; k0 < H; k0 += 32) {
        bf16x8 fa = *(const bf16x8*)&sA[lr][k0 + lg * 8];
        bf16x8 fh = *(const bf16x8*)&sH[lr][k0 + lg * 8];
#pragma unroll
        for (int g = 0; g < 6; g++) {
            const short* wb = ((g < 3) ? wihb : whhb) + (size_t)(g % 3) * H * H;
            bf16x8 fb[2];
#pragma unroll
            for (int ch = 0; ch < 2; ch++) {
                int c = jw + ch * 16 + lr;
                fb[ch] = *(const bf16x8*)(wb + (size_t)c * H + k0 + lg * 8);
            }
#pragma unroll
            for (int ch = 0; ch < 2; ch++)
                acc[g][ch] = __builtin_amdgcn_mfma_f32_16x16x32_bf16(
                    (g < 3) ? fa : fh, fb[ch], acc[g][ch], 0, 0, 0);
        }
    }

#pragma unroll
    for (int reg = 0; reg < 4; reg++) {
        int n = n0 + lg * 4 + reg;
#pragma unroll
        for (int ch = 0; ch < 2; ch++) {
            int jj = jw + ch * 16 + lr;
            float ir  = acc[0][ch][reg] + bih[jj];
            float iz  = acc[1][ch][reg] + bih[H + jj];
            float in_ = acc[2][ch][reg] + bih[2 * H + jj];
            float hr  = acc[3][ch][reg] + bhh[jj];
            float hz  = acc[4][ch][reg] + bhh[H + jj];
            float hn  = acc[5][ch][reg] + bhh[2 * H + jj];
            float r = 1.f / (1.f + expf(-(ir + hr)));
            float z = 1.f / (1.f + expf(-(iz + hz)));
            float nv = tanhf(in_ + r * hn);
            float ho = hcur[(size_t)n * H + jj];
            hnext[(size_t)n * H + jj] = (1.f - z) * nv + z * ho;
        }
    }
}

extern "C" void kernel_launch(void* const* d_in, const int* in_sizes, int n_in,
                              void* d_out, int out_size, void* d_ws, size_t ws_size,
                              hipStream_t stream) {
    const int*   x     = (const int*)d_in[0];
    const int*   ei    = (const int*)d_in[1];
    const int*   etype = (const int*)d_in[2];
    const float* emb   = (const float*)d_in[3];
    const float* Wm    = (const float*)d_in[4];
    const float* bm    = (const float*)d_in[5];
    const float* wih   = (const float*)d_in[6];
    const float* whh   = (const float*)d_in[7];
    const float* bih   = (const float*)d_in[8];
    const float* bhh   = (const float*)d_in[9];

    float* out = (float*)d_out;

    float* ws_h = (float*)d_ws;
    float* aggr = ws_h + (size_t)NN * H;
    short* wihb = (short*)(aggr + (size_t)NN * H);
    short* whhb = wihb + 3 * H * H;
    short* WmT  = whhb + 3 * H * H;
    int* hist_tb = (int*)(WmT + NT * H * H);
    int* off_tb  = hist_tb + NT * NB;
    int* pstart  = off_tb + NT * NB;
    int* perm    = pstart + 16;

    k_embed<<<2048, 256, 0, stream>>>(x, emb, ws_h);
    k_prep<<<720, 256, 0, stream>>>(wih, whh, Wm, wihb, whhb, WmT);

    k_hist<<<NB, CHUNK, 0, stream>>>(etype, hist_tb);
    k_scan<<<1, 64, 0, stream>>>(hist_tb, off_tb, pstart, perm);
    k_scatter<<<NB, CHUNK, 0, stream>>>(etype, off_tb, pstart, perm);

    const int MSG_BX = (NE + NT * 64 + 63) / 64;
    const int GRU_BX = NN / 16;   // 6250

    float* hcur = ws_h;
    float* hnxt = out;
    for (int s = 0; s < NSTEPS; s++) {
        hipMemsetAsync(aggr, 0, (size_t)NN * H * sizeof(float), stream);
        k_msg<<<MSG_BX, 512, 0, stream>>>(perm, pstart, ei, hcur, WmT, bm, aggr);
        k_gru<<<GRU_BX, 512, 0, stream>>>(aggr, hcur, hnxt, wihb, whhb, bih, bhh);
        float* tmp = hcur; hcur = hnxt; hnxt = tmp;
    }
}

// Round 4
// 3893.269 us; speedup vs baseline: 3.9199x; 1.1207x over previous
//
#include <hip/hip_runtime.h>
#include <math.h>

#define NN 100000
#define NE 300000
#define H 256
#define NT 8
#define NSTEPS 5
#define CHUNK 256
#define NB ((NE + CHUNK - 1) / CHUNK)
#define RS 264   // LDS row stride in shorts

typedef __attribute__((ext_vector_type(8))) short bf16x8;
typedef __attribute__((ext_vector_type(4))) float f32x4;

static __device__ __forceinline__ short f2bf(float f) {
    union { float f; unsigned u; } v; v.f = f;
    unsigned r = (v.u + 0x7FFFu + ((v.u >> 16) & 1u)) >> 16;
    return (short)r;
}
static __device__ __forceinline__ float bf2f(short s) {
    union { unsigned u; float f; } v; v.u = ((unsigned)(unsigned short)s) << 16;
    return v.f;
}

// ---------------- embedding gather: h0 = emb[x] (fp32) ----------------
__global__ void k_embed(const int* __restrict__ x, const float* __restrict__ emb,
                        float* __restrict__ h) {
    int total = NN * (H / 4);
    for (int idx = blockIdx.x * blockDim.x + threadIdx.x; idx < total;
         idx += gridDim.x * blockDim.x) {
        int node = idx >> 6;
        int j4   = idx & 63;
        reinterpret_cast<float4*>(h)[idx] =
            reinterpret_cast<const float4*>(emb + (size_t)x[node] * H)[j4];
    }
}

// ---------------- weight prep: bf16 copies (W_msg transposed) ----------------
__global__ void k_prep(const float* __restrict__ wih, const float* __restrict__ whh,
                       const float* __restrict__ Wm,
                       short* __restrict__ wihb, short* __restrict__ whhb,
                       short* __restrict__ WmT) {
    int n1 = 3 * H * H;
    int n2 = NT * H * H;
    for (int i = blockIdx.x * blockDim.x + threadIdx.x; i < n1 + n2;
         i += gridDim.x * blockDim.x) {
        if (i < n1) {
            wihb[i] = f2bf(wih[i]);
            whhb[i] = f2bf(whh[i]);
        } else {
            int idx = i - n1;
            int t = idx >> 16, rem = idx & 65535;
            int j = rem >> 8, k = rem & 255;
            WmT[idx] = f2bf(Wm[(size_t)t * H * H + (size_t)k * H + j]);
        }
    }
}

// ---------------- stable counting sort of edges by type ----------------
__global__ void k_hist(const int* __restrict__ etype, int* __restrict__ hist_tb) {
    __shared__ int lh[NT];
    int b = blockIdx.x;
    if (threadIdx.x < NT) lh[threadIdx.x] = 0;
    __syncthreads();
    int e = b * CHUNK + threadIdx.x;
    if (e < NE) atomicAdd(&lh[etype[e]], 1);
    __syncthreads();
    if (threadIdx.x < NT) hist_tb[threadIdx.x * NB + b] = lh[threadIdx.x];
}

__global__ void k_scan(const int* __restrict__ hist_tb, int* __restrict__ off_tb,
                       int* __restrict__ pstart, int* __restrict__ perm) {
    __shared__ int total[NT];
    int t = threadIdx.x;
    if (t < NT) {
        int run = 0;
        for (int b = 0; b < NB; b++) {
            off_tb[t * NB + b] = run;
            run += hist_tb[t * NB + b];
        }
        total[t] = run;
    }
    __syncthreads();
    if (t == 0) {
        int p = 0;
        for (int tt = 0; tt < NT; tt++) {
            pstart[tt] = p;
            int padded = (total[tt] + 127) / 128 * 128;   // 128-aligned segments
            for (int q = total[tt]; q < padded; q++) perm[p + q] = -1;
            p += padded;
        }
        pstart[NT] = p;
    }
}

__global__ void k_scatter(const int* __restrict__ etype, const int* __restrict__ off_tb,
                          const int* __restrict__ pstart, int* __restrict__ perm) {
    __shared__ int st[CHUNK];
    int b = blockIdx.x;
    int e = b * CHUNK + threadIdx.x;
    st[threadIdx.x] = (e < NE) ? etype[e] : -1;
    __syncthreads();
    if (e < NE) {
        int t = st[threadIdx.x];
        int r = 0;
        for (int i = 0; i < threadIdx.x; i++) r += (st[i] == t);
        perm[pstart[t] + off_tb[t * NB + b] + r] = e;
    }
}

// ---------------- message GEMM (MFMA): aggr[dst] += h[src] @ W[t] + b[t] ----
// Block: 128 edges x 256 cols, 512 threads (8 waves x 32-col slice).
__global__ __launch_bounds__(512) void k_msg(
    const int* __restrict__ perm, const int* __restrict__ pstart,
    const int* __restrict__ ei, const float* __restrict__ hcur,
    const short* __restrict__ WmT, const float* __restrict__ bm,
    float* __restrict__ aggr) {
    int Epad = pstart[NT];
    int e0 = blockIdx.x * 128;
    if (e0 >= Epad) return;
    int t = 0;
    while (t < NT - 1 && e0 >= pstart[t + 1]) t++;

    __shared__ short sA[128][RS];
    __shared__ int se[128], de[128];

    int tid = threadIdx.x;
    if (tid < 128) {
        int eid = perm[e0 + tid];
        se[tid] = (eid >= 0) ? ei[eid] : -1;
        de[tid] = (eid >= 0) ? ei[NE + eid] : 0;
    }
    __syncthreads();

    // stage h[src] tile -> LDS bf16: 1024 tasks of (row, 32-col chunk)
    for (int task = tid; task < 1024; task += 512) {
        int r = task >> 3, c0 = (task & 7) * 32;
        int s = se[r];
        short tmp[32];
        if (s >= 0) {
            const float* p = hcur + (size_t)s * H + c0;
#pragma unroll
            for (int i = 0; i < 32; i++) tmp[i] = f2bf(p[i]);
        } else {
#pragma unroll
            for (int i = 0; i < 32; i++) tmp[i] = 0;
        }
#pragma unroll
        for (int i = 0; i < 4; i++)
            *(bf16x8*)&sA[r][c0 + i * 8] = *(bf16x8*)&tmp[i * 8];
    }
    __syncthreads();

    int wid = tid >> 6, lane = tid & 63;
    int jw = wid * 32;
    int lr = lane & 15, lg = lane >> 4;

    const short* wt = WmT + (size_t)t * H * H;   // [j][k]
    f32x4 acc[8][2] = {};

    for (int k0 = 0; k0 < H; k0 += 32) {
        bf16x8 fb[2];
#pragma unroll
        for (int ch = 0; ch < 2; ch++) {
            int c = jw + ch * 16 + lr;
            fb[ch] = *(const bf16x8*)(wt + (size_t)c * H + k0 + lg * 8);
        }
#pragma unroll
        for (int rh = 0; rh < 8; rh++) {
            bf16x8 fa = *(const bf16x8*)&sA[rh * 16 + lr][k0 + lg * 8];
#pragma unroll
            for (int ch = 0; ch < 2; ch++)
                acc[rh][ch] = __builtin_amdgcn_mfma_f32_16x16x32_bf16(
                    fa, fb[ch], acc[rh][ch], 0, 0, 0);
        }
    }

#pragma unroll
    for (int rh = 0; rh < 8; rh++) {
#pragma unroll
        for (int reg = 0; reg < 4; reg++) {
            int row = rh * 16 + lg * 4 + reg;
            int s = se[row];
            if (s < 0) continue;
            int d = de[row];
#pragma unroll
            for (int ch = 0; ch < 2; ch++) {
                int jj = jw + ch * 16 + lr;
                atomicAdd(&aggr[(size_t)d * H + jj], acc[rh][ch][reg] + bm[t * H + jj]);
            }
        }
    }
}

// ---------------- fused GRU (MFMA): h' = GRUCell(aggr, h) ----------------
// Block: 64 nodes x all 256 cols x 6 gates, 512 threads (8 waves x 32-col slice).
// acc[6][4][2] f32x4 = 192 VGPR; per K-iter 48 MFMA : 12 B-loads.
__global__ __launch_bounds__(512) void k_gru(
    const float* __restrict__ aggr, const float* __restrict__ hcur,
    float* __restrict__ hnext,
    const short* __restrict__ wihb, const short* __restrict__ whhb,
    const float* __restrict__ bih, const float* __restrict__ bhh) {
    int n0 = blockIdx.x * 64;
    int tid = threadIdx.x;

    __shared__ short sA[64][RS];
    __shared__ short sH[64][RS];

    // stage: 1024 tasks = 2 mats x 64 rows x 8 col-chunks(32)
    for (int task = tid; task < 1024; task += 512) {
        int which = task >> 9;          // 0: aggr, 1: hcur
        int t2 = task & 511;
        int r = t2 >> 3, c0 = (t2 & 7) * 32;
        int n = n0 + r;
        short tmp[32];
        if (n < NN) {
            const float* src = (which ? hcur : aggr) + (size_t)n * H + c0;
#pragma unroll
            for (int i = 0; i < 32; i++) tmp[i] = f2bf(src[i]);
        } else {
#pragma unroll
            for (int i = 0; i < 32; i++) tmp[i] = 0;
        }
        short* dst = (which ? &sH[r][c0] : &sA[r][c0]);
#pragma unroll
        for (int i = 0; i < 4; i++)
            *(bf16x8*)(dst + i * 8) = *(bf16x8*)&tmp[i * 8];
    }
    __syncthreads();

    int wid = tid >> 6, lane = tid & 63;
    int jw = wid * 32;
    int lr = lane & 15, lg = lane >> 4;

    f32x4 acc[6][4][2] = {};

    for (int k0 = 0; k0 < H; k0 += 32) {
        bf16x8 fa[4], fh[4];
#pragma unroll
        for (int rh = 0; rh < 4; rh++) {
            fa[rh] = *(const bf16x8*)&sA[rh * 16 + lr][k0 + lg * 8];
            fh[rh] = *(const bf16x8*)&sH[rh * 16 + lr][k0 + lg * 8];
        }
#pragma unroll
        for (int g = 0; g < 6; g++) {
            const short* wb = ((g < 3) ? wihb : whhb) + (size_t)(g % 3) * H * H;
            bf16x8 fb[2];
#pragma unroll
            for (int ch = 0; ch < 2; ch++) {
                int c = jw + ch * 16 + lr;
                fb[ch] = *(const bf16x8*)(wb + (size_t)c * H + k0 + lg * 8);
            }
#pragma unroll
            for (int rh = 0; rh < 4; rh++)
#pragma unroll
                for (int ch = 0; ch < 2; ch++)
                    acc[g][rh][ch] = __builtin_amdgcn_mfma_f32_16x16x32_bf16(
                        (g < 3) ? fa[rh] : fh[rh], fb[ch], acc[g][rh][ch], 0, 0, 0);
        }
    }

#pragma unroll
    for (int rh = 0; rh < 4; rh++) {
#pragma unroll
        for (int reg = 0; reg < 4; reg++) {
            int row = rh * 16 + lg * 4 + reg;
            int n = n0 + row;
            if (n >= NN) continue;
#pragma unroll
            for (int ch = 0; ch < 2; ch++) {
                int jj = jw + ch * 16 + lr;
                float ir  = acc[0][rh][ch][reg] + bih[jj];
                float iz  = acc[1][rh][ch][reg] + bih[H + jj];
                float in_ = acc[2][rh][ch][reg] + bih[2 * H + jj];
                float hr  = acc[3][rh][ch][reg] + bhh[jj];
                float hz  = acc[4][rh][ch][reg] + bhh[H + jj];
                float hn  = acc[5][rh][ch][reg] + bhh[2 * H + jj];
                float r = 1.f / (1.f + expf(-(ir + hr)));
                float z = 1.f / (1.f + expf(-(iz + hz)));
                float nv = tanhf(in_ + r * hn);
                float ho = bf2f(sH[row][jj]);
                hnext[(size_t)n * H + jj] = (1.f - z) * nv + z * ho;
            }
        }
    }
}

extern "C" void kernel_launch(void* const* d_in, const int* in_sizes, int n_in,
                              void* d_out, int out_size, void* d_ws, size_t ws_size,
                              hipStream_t stream) {
    const int*   x     = (const int*)d_in[0];
    const int*   ei    = (const int*)d_in[1];
    const int*   etype = (const int*)d_in[2];
    const float* emb   = (const float*)d_in[3];
    const float* Wm    = (const float*)d_in[4];
    const float* bm    = (const float*)d_in[5];
    const float* wih   = (const float*)d_in[6];
    const float* whh   = (const float*)d_in[7];
    const float* bih   = (const float*)d_in[8];
    const float* bhh   = (const float*)d_in[9];

    float* out = (float*)d_out;

    float* ws_h = (float*)d_ws;
    float* aggr = ws_h + (size_t)NN * H;
    short* wihb = (short*)(aggr + (size_t)NN * H);
    short* whhb = wihb + 3 * H * H;
    short* WmT  = whhb + 3 * H * H;
    int* hist_tb = (int*)(WmT + NT * H * H);
    int* off_tb  = hist_tb + NT * NB;
    int* pstart  = off_tb + NT * NB;
    int* perm    = pstart + 16;                  // [NE + NT*128]

    k_embed<<<2048, 256, 0, stream>>>(x, emb, ws_h);
    k_prep<<<720, 256, 0, stream>>>(wih, whh, Wm, wihb, whhb, WmT);

    k_hist<<<NB, CHUNK, 0, stream>>>(etype, hist_tb);
    k_scan<<<1, 64, 0, stream>>>(hist_tb, off_tb, pstart, perm);
    k_scatter<<<NB, CHUNK, 0, stream>>>(etype, off_tb, pstart, perm);

    const int MSG_BX = (NE + NT * 128 + 127) / 128;  // covers max padded length
    const int GRU_BX = (NN + 63) / 64;               // 1563

    float* hcur = ws_h;
    float* hnxt = out;
    for (int s = 0; s < NSTEPS; s++) {
        hipMemsetAsync(aggr, 0, (size_t)NN * H * sizeof(float), stream);
        k_msg<<<MSG_BX, 512, 0, stream>>>(perm, pstart, ei, hcur, WmT, bm, aggr);
        k_gru<<<GRU_BX, 512, 0, stream>>>(aggr, hcur, hnxt, wihb, whhb, bih, bhh);
        float* tmp = hcur; hcur = hnxt; hnxt = tmp;
    }
}

// Round 5
// 3886.514 us; speedup vs baseline: 3.9267x; 1.0017x over previous
//
#include <hip/hip_runtime.h>
#include <math.h>

#define NN 100000
#define NE 300000
#define H 256
#define NT 8
#define NSTEPS 5
#define CHUNK 256
#define NB ((NE + CHUNK - 1) / CHUNK)
#define RS 264   // LDS row stride in shorts

typedef __attribute__((ext_vector_type(8))) short bf16x8;
typedef __attribute__((ext_vector_type(4))) float f32x4;

static __device__ __forceinline__ short f2bf(float f) {
    union { float f; unsigned u; } v; v.f = f;
    unsigned r = (v.u + 0x7FFFu + ((v.u >> 16) & 1u)) >> 16;
    return (short)r;
}
static __device__ __forceinline__ float bf2f(short s) {
    union { unsigned u; float f; } v; v.u = ((unsigned)(unsigned short)s) << 16;
    return v.f;
}

// ---------------- embedding gather: h0 = emb[x] (fp32) ----------------
__global__ void k_embed(const int* __restrict__ x, const float* __restrict__ emb,
                        float* __restrict__ h) {
    int total = NN * (H / 4);
    for (int idx = blockIdx.x * blockDim.x + threadIdx.x; idx < total;
         idx += gridDim.x * blockDim.x) {
        int node = idx >> 6;
        int j4   = idx & 63;
        reinterpret_cast<float4*>(h)[idx] =
            reinterpret_cast<const float4*>(emb + (size_t)x[node] * H)[j4];
    }
}

// ---------------- weight prep: bf16 copies (W_msg transposed) ----------------
__global__ void k_prep(const float* __restrict__ wih, const float* __restrict__ whh,
                       const float* __restrict__ Wm,
                       short* __restrict__ wihb, short* __restrict__ whhb,
                       short* __restrict__ WmT) {
    int n1 = 3 * H * H;
    int n2 = NT * H * H;
    for (int i = blockIdx.x * blockDim.x + threadIdx.x; i < n1 + n2;
         i += gridDim.x * blockDim.x) {
        if (i < n1) {
            wihb[i] = f2bf(wih[i]);
            whhb[i] = f2bf(whh[i]);
        } else {
            int idx = i - n1;
            int t = idx >> 16, rem = idx & 65535;
            int j = rem >> 8, k = rem & 255;
            WmT[idx] = f2bf(Wm[(size_t)t * H * H + (size_t)k * H + j]);
        }
    }
}

// ---------------- stable counting sort of edges by type ----------------
__global__ void k_hist(const int* __restrict__ etype, int* __restrict__ hist_tb) {
    __shared__ int lh[NT];
    int b = blockIdx.x;
    if (threadIdx.x < NT) lh[threadIdx.x] = 0;
    __syncthreads();
    int e = b * CHUNK + threadIdx.x;
    if (e < NE) atomicAdd(&lh[etype[e]], 1);
    __syncthreads();
    if (threadIdx.x < NT) hist_tb[threadIdx.x * NB + b] = lh[threadIdx.x];
}

__global__ void k_scan(const int* __restrict__ hist_tb, int* __restrict__ off_tb,
                       int* __restrict__ pstart, int* __restrict__ perm) {
    __shared__ int total[NT];
    int t = threadIdx.x;
    if (t < NT) {
        int run = 0;
        for (int b = 0; b < NB; b++) {
            off_tb[t * NB + b] = run;
            run += hist_tb[t * NB + b];
        }
        total[t] = run;
    }
    __syncthreads();
    if (t == 0) {
        int p = 0;
        for (int tt = 0; tt < NT; tt++) {
            pstart[tt] = p;
            int padded = (total[tt] + 127) / 128 * 128;
            for (int q = total[tt]; q < padded; q++) perm[p + q] = -1;
            p += padded;
        }
        pstart[NT] = p;
    }
}

__global__ void k_scatter(const int* __restrict__ etype, const int* __restrict__ off_tb,
                          const int* __restrict__ pstart, int* __restrict__ perm) {
    __shared__ int st[CHUNK];
    int b = blockIdx.x;
    int e = b * CHUNK + threadIdx.x;
    st[threadIdx.x] = (e < NE) ? etype[e] : -1;
    __syncthreads();
    if (e < NE) {
        int t = st[threadIdx.x];
        int r = 0;
        for (int i = 0; i < threadIdx.x; i++) r += (st[i] == t);
        perm[pstart[t] + off_tb[t * NB + b] + r] = e;
    }
}

// ---------------- message GEMM (MFMA): aggr[dst] += h[src] @ W[t] + b[t] ----
// Block: 128 edges x 256 cols, 512 threads (8 waves x 32-col slice).
__global__ __launch_bounds__(512) void k_msg(
    const int* __restrict__ perm, const int* __restrict__ pstart,
    const int* __restrict__ ei, const float* __restrict__ hcur,
    const short* __restrict__ WmT, const float* __restrict__ bm,
    float* __restrict__ aggr) {
    int Epad = pstart[NT];
    int e0 = blockIdx.x * 128;
    if (e0 >= Epad) return;
    int t = 0;
    while (t < NT - 1 && e0 >= pstart[t + 1]) t++;

    __shared__ short sA[128][RS];
    __shared__ int se[128], de[128];

    int tid = threadIdx.x;
    if (tid < 128) {
        int eid = perm[e0 + tid];
        se[tid] = (eid >= 0) ? ei[eid] : -1;
        de[tid] = (eid >= 0) ? ei[NE + eid] : 0;
    }
    __syncthreads();

    // stage h[src] tile -> LDS bf16 (float4-vectorized)
    for (int task = tid; task < 1024; task += 512) {
        int r = task >> 3, c0 = (task & 7) * 32;
        int s = se[r];
        short tmp[32];
        if (s >= 0) {
            const float4* p4 = reinterpret_cast<const float4*>(hcur + (size_t)s * H + c0);
#pragma unroll
            for (int i = 0; i < 8; i++) {
                float4 u = p4[i];
                tmp[i * 4 + 0] = f2bf(u.x); tmp[i * 4 + 1] = f2bf(u.y);
                tmp[i * 4 + 2] = f2bf(u.z); tmp[i * 4 + 3] = f2bf(u.w);
            }
        } else {
#pragma unroll
            for (int i = 0; i < 32; i++) tmp[i] = 0;
        }
#pragma unroll
        for (int i = 0; i < 4; i++)
            *(bf16x8*)&sA[r][c0 + i * 8] = *(bf16x8*)&tmp[i * 8];
    }
    __syncthreads();

    int wid = tid >> 6, lane = tid & 63;
    int jw = wid * 32;
    int lr = lane & 15, lg = lane >> 4;

    const short* wt = WmT + (size_t)t * H * H;   // [j][k]
    f32x4 acc[8][2] = {};

    for (int k0 = 0; k0 < H; k0 += 32) {
        bf16x8 fb[2];
#pragma unroll
        for (int ch = 0; ch < 2; ch++) {
            int c = jw + ch * 16 + lr;
            fb[ch] = *(const bf16x8*)(wt + (size_t)c * H + k0 + lg * 8);
        }
#pragma unroll
        for (int rh = 0; rh < 8; rh++) {
            bf16x8 fa = *(const bf16x8*)&sA[rh * 16 + lr][k0 + lg * 8];
#pragma unroll
            for (int ch = 0; ch < 2; ch++)
                acc[rh][ch] = __builtin_amdgcn_mfma_f32_16x16x32_bf16(
                    fa, fb[ch], acc[rh][ch], 0, 0, 0);
        }
    }

#pragma unroll
    for (int rh = 0; rh < 8; rh++) {
#pragma unroll
        for (int reg = 0; reg < 4; reg++) {
            int row = rh * 16 + lg * 4 + reg;
            int s = se[row];
            if (s < 0) continue;
            int d = de[row];
#pragma unroll
            for (int ch = 0; ch < 2; ch++) {
                int jj = jw + ch * 16 + lr;
                atomicAdd(&aggr[(size_t)d * H + jj], acc[rh][ch][reg] + bm[t * H + jj]);
            }
        }
    }
}

// ---------------- fused GRU (MFMA): h' = GRUCell(aggr, h) ----------------
// Block: 64 nodes x 256 cols x 6 gates, 512 threads (8 waves x 32-col slice).
// acc[6][4][2] f32x4 = 192 VGPR -> needs the 256-VGPR budget: launch_bounds(512,2).
__global__ __launch_bounds__(512, 2) void k_gru(
    const float* __restrict__ aggr, const float* __restrict__ hcur,
    float* __restrict__ hnext,
    const short* __restrict__ wihb, const short* __restrict__ whhb,
    const float* __restrict__ bih, const float* __restrict__ bhh) {
    int n0 = blockIdx.x * 64;
    int tid = threadIdx.x;

    __shared__ short sA[64][RS];
    __shared__ short sH[64][RS];

    // stage: 1024 tasks = 2 mats x 64 rows x 8 col-chunks(32), float4-vectorized
    for (int task = tid; task < 1024; task += 512) {
        int which = task >> 9;
        int t2 = task & 511;
        int r = t2 >> 3, c0 = (t2 & 7) * 32;
        int n = n0 + r;
        short tmp[32];
        if (n < NN) {
            const float4* p4 = reinterpret_cast<const float4*>(
                (which ? hcur : aggr) + (size_t)n * H + c0);
#pragma unroll
            for (int i = 0; i < 8; i++) {
                float4 u = p4[i];
                tmp[i * 4 + 0] = f2bf(u.x); tmp[i * 4 + 1] = f2bf(u.y);
                tmp[i * 4 + 2] = f2bf(u.z); tmp[i * 4 + 3] = f2bf(u.w);
            }
        } else {
#pragma unroll
            for (int i = 0; i < 32; i++) tmp[i] = 0;
        }
        short* dst = (which ? &sH[r][c0] : &sA[r][c0]);
#pragma unroll
        for (int i = 0; i < 4; i++)
            *(bf16x8*)(dst + i * 8) = *(bf16x8*)&tmp[i * 8];
    }
    __syncthreads();

    int wid = tid >> 6, lane = tid & 63;
    int jw = wid * 32;
    int lr = lane & 15, lg = lane >> 4;

    f32x4 acc[6][4][2] = {};

    for (int k0 = 0; k0 < H; k0 += 32) {
        bf16x8 fa[4], fh[4];
#pragma unroll
        for (int rh = 0; rh < 4; rh++) {
            fa[rh] = *(const bf16x8*)&sA[rh * 16 + lr][k0 + lg * 8];
            fh[rh] = *(const bf16x8*)&sH[rh * 16 + lr][k0 + lg * 8];
        }
#pragma unroll
        for (int g = 0; g < 6; g++) {
            const short* wb = ((g < 3) ? wihb : whhb) + (size_t)(g % 3) * H * H;
            bf16x8 fb[2];
#pragma unroll
            for (int ch = 0; ch < 2; ch++) {
                int c = jw + ch * 16 + lr;
                fb[ch] = *(const bf16x8*)(wb + (size_t)c * H + k0 + lg * 8);
            }
#pragma unroll
            for (int rh = 0; rh < 4; rh++)
#pragma unroll
                for (int ch = 0; ch < 2; ch++)
                    acc[g][rh][ch] = __builtin_amdgcn_mfma_f32_16x16x32_bf16(
                        (g < 3) ? fa[rh] : fh[rh], fb[ch], acc[g][rh][ch], 0, 0, 0);
        }
    }

#pragma unroll
    for (int rh = 0; rh < 4; rh++) {
#pragma unroll
        for (int reg = 0; reg < 4; reg++) {
            int row = rh * 16 + lg * 4 + reg;
            int n = n0 + row;
            if (n >= NN) continue;
#pragma unroll
            for (int ch = 0; ch < 2; ch++) {
                int jj = jw + ch * 16 + lr;
                float ir  = acc[0][rh][ch][reg] + bih[jj];
                float iz  = acc[1][rh][ch][reg] + bih[H + jj];
                float in_ = acc[2][rh][ch][reg] + bih[2 * H + jj];
                float hr  = acc[3][rh][ch][reg] + bhh[jj];
                float hz  = acc[4][rh][ch][reg] + bhh[H + jj];
                float hn  = acc[5][rh][ch][reg] + bhh[2 * H + jj];
                float r = 1.f / (1.f + expf(-(ir + hr)));
                float z = 1.f / (1.f + expf(-(iz + hz)));
                float nv = tanhf(in_ + r * hn);
                float ho = bf2f(sH[row][jj]);
                hnext[(size_t)n * H + jj] = (1.f - z) * nv + z * ho;
            }
        }
    }
}

extern "C" void kernel_launch(void* const* d_in, const int* in_sizes, int n_in,
                              void* d_out, int out_size, void* d_ws, size_t ws_size,
                              hipStream_t stream) {
    const int*   x     = (const int*)d_in[0];
    const int*   ei    = (const int*)d_in[1];
    const int*   etype = (const int*)d_in[2];
    const float* emb   = (const float*)d_in[3];
    const float* Wm    = (const float*)d_in[4];
    const float* bm    = (const float*)d_in[5];
    const float* wih   = (const float*)d_in[6];
    const float* whh   = (const float*)d_in[7];
    const float* bih   = (const float*)d_in[8];
    const float* bhh   = (const float*)d_in[9];

    float* out = (float*)d_out;

    float* ws_h = (float*)d_ws;
    float* aggr = ws_h + (size_t)NN * H;
    short* wihb = (short*)(aggr + (size_t)NN * H);
    short* whhb = wihb + 3 * H * H;
    short* WmT  = whhb + 3 * H * H;
    int* hist_tb = (int*)(WmT + NT * H * H);
    int* off_tb  = hist_tb + NT * NB;
    int* pstart  = off_tb + NT * NB;
    int* perm    = pstart + 16;

    k_embed<<<2048, 256, 0, stream>>>(x, emb, ws_h);
    k_prep<<<720, 256, 0, stream>>>(wih, whh, Wm, wihb, whhb, WmT);

    k_hist<<<NB, CHUNK, 0, stream>>>(etype, hist_tb);
    k_scan<<<1, 64, 0, stream>>>(hist_tb, off_tb, pstart, perm);
    k_scatter<<<NB, CHUNK, 0, stream>>>(etype, off_tb, pstart, perm);

    const int MSG_BX = (NE + NT * 128 + 127) / 128;
    const int GRU_BX = (NN + 63) / 64;

    float* hcur = ws_h;
    float* hnxt = out;
    for (int s = 0; s < NSTEPS; s++) {
        hipMemsetAsync(aggr, 0, (size_t)NN * H * sizeof(float), stream);
        k_msg<<<MSG_BX, 512, 0, stream>>>(perm, pstart, ei, hcur, WmT, bm, aggr);
        k_gru<<<GRU_BX, 512, 0, stream>>>(aggr, hcur, hnxt, wihb, whhb, bih, bhh);
        float* tmp = hcur; hcur = hnxt; hnxt = tmp;
    }
}

// Round 6
// 3784.616 us; speedup vs baseline: 4.0325x; 1.0269x over previous
//
#include <hip/hip_runtime.h>
#include <math.h>

#define NN 100000
#define NE 300000
#define H 256
#define NT 8
#define NSTEPS 5
#define CHUNK 256
#define NB ((NE + CHUNK - 1) / CHUNK)
#define RS 264   // LDS row stride in shorts

typedef __attribute__((ext_vector_type(8))) short bf16x8;
typedef __attribute__((ext_vector_type(4))) float f32x4;

static __device__ __forceinline__ short f2bf(float f) {
    union { float f; unsigned u; } v; v.f = f;
    unsigned r = (v.u + 0x7FFFu + ((v.u >> 16) & 1u)) >> 16;
    return (short)r;
}
static __device__ __forceinline__ float bf2f(short s) {
    union { unsigned u; float f; } v; v.u = ((unsigned)(unsigned short)s) << 16;
    return v.f;
}

// ---------------- embedding gather: h0 = emb[x] (fp32) ----------------
__global__ void k_embed(const int* __restrict__ x, const float* __restrict__ emb,
                        float* __restrict__ h) {
    int total = NN * (H / 4);
    for (int idx = blockIdx.x * blockDim.x + threadIdx.x; idx < total;
         idx += gridDim.x * blockDim.x) {
        int node = idx >> 6;
        int j4   = idx & 63;
        reinterpret_cast<float4*>(h)[idx] =
            reinterpret_cast<const float4*>(emb + (size_t)x[node] * H)[j4];
    }
}

// ---------------- weight prep: bf16 copies (W_msg transposed) ----------------
__global__ void k_prep(const float* __restrict__ wih, const float* __restrict__ whh,
                       const float* __restrict__ Wm,
                       short* __restrict__ wihb, short* __restrict__ whhb,
                       short* __restrict__ WmT) {
    int n1 = 3 * H * H;
    int n2 = NT * H * H;
    for (int i = blockIdx.x * blockDim.x + threadIdx.x; i < n1 + n2;
         i += gridDim.x * blockDim.x) {
        if (i < n1) {
            wihb[i] = f2bf(wih[i]);
            whhb[i] = f2bf(whh[i]);
        } else {
            int idx = i - n1;
            int t = idx >> 16, rem = idx & 65535;
            int j = rem >> 8, k = rem & 255;
            WmT[idx] = f2bf(Wm[(size_t)t * H * H + (size_t)k * H + j]);
        }
    }
}

// ---------------- stable counting sort of edges by type ----------------
__global__ void k_hist(const int* __restrict__ etype, int* __restrict__ hist_tb) {
    __shared__ int lh[NT];
    int b = blockIdx.x;
    if (threadIdx.x < NT) lh[threadIdx.x] = 0;
    __syncthreads();
    int e = b * CHUNK + threadIdx.x;
    if (e < NE) atomicAdd(&lh[etype[e]], 1);
    __syncthreads();
    if (threadIdx.x < NT) hist_tb[threadIdx.x * NB + b] = lh[threadIdx.x];
}

__global__ void k_scan(const int* __restrict__ hist_tb, int* __restrict__ off_tb,
                       int* __restrict__ pstart, int* __restrict__ perm) {
    __shared__ int total[NT];
    int t = threadIdx.x;
    if (t < NT) {
        int run = 0;
        for (int b = 0; b < NB; b++) {
            off_tb[t * NB + b] = run;
            run += hist_tb[t * NB + b];
        }
        total[t] = run;
    }
    __syncthreads();
    if (t == 0) {
        int p = 0;
        for (int tt = 0; tt < NT; tt++) {
            pstart[tt] = p;
            int padded = (total[tt] + 127) / 128 * 128;
            for (int q = total[tt]; q < padded; q++) perm[p + q] = -1;
            p += padded;
        }
        pstart[NT] = p;
    }
}

__global__ void k_scatter(const int* __restrict__ etype, const int* __restrict__ off_tb,
                          const int* __restrict__ pstart, int* __restrict__ perm) {
    __shared__ int st[CHUNK];
    int b = blockIdx.x;
    int e = b * CHUNK + threadIdx.x;
    st[threadIdx.x] = (e < NE) ? etype[e] : -1;
    __syncthreads();
    if (e < NE) {
        int t = st[threadIdx.x];
        int r = 0;
        for (int i = 0; i < threadIdx.x; i++) r += (st[i] == t);
        perm[pstart[t] + off_tb[t * NB + b] + r] = e;
    }
}

// ---------------- message GEMM (MFMA): aggr[dst] += h[src] @ W[t] + b[t] ----
// Block: 128 edges x 256 cols, 512 threads (8 waves x 32-col slice).
__global__ __launch_bounds__(512) void k_msg(
    const int* __restrict__ perm, const int* __restrict__ pstart,
    const int* __restrict__ ei, const float* __restrict__ hcur,
    const short* __restrict__ WmT, const float* __restrict__ bm,
    float* __restrict__ aggr) {
    int Epad = pstart[NT];
    int e0 = blockIdx.x * 128;
    if (e0 >= Epad) return;
    int t = 0;
    while (t < NT - 1 && e0 >= pstart[t + 1]) t++;

    __shared__ short sA[128][RS];
    __shared__ int se[128], de[128];

    int tid = threadIdx.x;
    if (tid < 128) {
        int eid = perm[e0 + tid];
        se[tid] = (eid >= 0) ? ei[eid] : -1;
        de[tid] = (eid >= 0) ? ei[NE + eid] : 0;
    }
    __syncthreads();

    // stage h[src] tile -> LDS bf16 (float4-vectorized)
    for (int task = tid; task < 1024; task += 512) {
        int r = task >> 3, c0 = (task & 7) * 32;
        int s = se[r];
        short tmp[32];
        if (s >= 0) {
            const float4* p4 = reinterpret_cast<const float4*>(hcur + (size_t)s * H + c0);
#pragma unroll
            for (int i = 0; i < 8; i++) {
                float4 u = p4[i];
                tmp[i * 4 + 0] = f2bf(u.x); tmp[i * 4 + 1] = f2bf(u.y);
                tmp[i * 4 + 2] = f2bf(u.z); tmp[i * 4 + 3] = f2bf(u.w);
            }
        } else {
#pragma unroll
            for (int i = 0; i < 32; i++) tmp[i] = 0;
        }
#pragma unroll
        for (int i = 0; i < 4; i++)
            *(bf16x8*)&sA[r][c0 + i * 8] = *(bf16x8*)&tmp[i * 8];
    }
    __syncthreads();

    int wid = tid >> 6, lane = tid & 63;
    int jw = wid * 32;
    int lr = lane & 15, lg = lane >> 4;

    const short* wt = WmT + (size_t)t * H * H;   // [j][k]
    f32x4 acc[8][2] = {};

    for (int k0 = 0; k0 < H; k0 += 32) {
        bf16x8 fb[2];
#pragma unroll
        for (int ch = 0; ch < 2; ch++) {
            int c = jw + ch * 16 + lr;
            fb[ch] = *(const bf16x8*)(wt + (size_t)c * H + k0 + lg * 8);
        }
#pragma unroll
        for (int rh = 0; rh < 8; rh++) {
            bf16x8 fa = *(const bf16x8*)&sA[rh * 16 + lr][k0 + lg * 8];
#pragma unroll
            for (int ch = 0; ch < 2; ch++)
                acc[rh][ch] = __builtin_amdgcn_mfma_f32_16x16x32_bf16(
                    fa, fb[ch], acc[rh][ch], 0, 0, 0);
        }
    }

#pragma unroll
    for (int rh = 0; rh < 8; rh++) {
#pragma unroll
        for (int reg = 0; reg < 4; reg++) {
            int row = rh * 16 + lg * 4 + reg;
            int s = se[row];
            if (s < 0) continue;
            int d = de[row];
#pragma unroll
            for (int ch = 0; ch < 2; ch++) {
                int jj = jw + ch * 16 + lr;
                atomicAdd(&aggr[(size_t)d * H + jj], acc[rh][ch][reg] + bm[t * H + jj]);
            }
        }
    }
}

// ---------------- fused GRU (MFMA): h' = GRUCell(aggr, h) ----------------
// Block: 64 nodes x 256 cols x 6 gates, 512 threads (8 waves x 32-col slice).
// acc[6][4][2] f32x4 = 192 VGPR. Round-5 evidence: hipcc treats the 2nd
// launch_bounds arg as min BLOCKS/CU (cap = 512 VGPR-file / (blocks*2 waves/SIMD)).
// (512,2) -> 128-VGPR cap -> spills (653 MB scratch writes). (512,1) -> 256 cap.
__global__ __launch_bounds__(512, 1) void k_gru(
    const float* __restrict__ aggr, const float* __restrict__ hcur,
    float* __restrict__ hnext,
    const short* __restrict__ wihb, const short* __restrict__ whhb,
    const float* __restrict__ bih, const float* __restrict__ bhh) {
    int n0 = blockIdx.x * 64;
    int tid = threadIdx.x;

    __shared__ short sA[64][RS];
    __shared__ short sH[64][RS];

    // stage: 1024 tasks = 2 mats x 64 rows x 8 col-chunks(32), float4-vectorized
    for (int task = tid; task < 1024; task += 512) {
        int which = task >> 9;
        int t2 = task & 511;
        int r = t2 >> 3, c0 = (t2 & 7) * 32;
        int n = n0 + r;
        short tmp[32];
        if (n < NN) {
            const float4* p4 = reinterpret_cast<const float4*>(
                (which ? hcur : aggr) + (size_t)n * H + c0);
#pragma unroll
            for (int i = 0; i < 8; i++) {
                float4 u = p4[i];
                tmp[i * 4 + 0] = f2bf(u.x); tmp[i * 4 + 1] = f2bf(u.y);
                tmp[i * 4 + 2] = f2bf(u.z); tmp[i * 4 + 3] = f2bf(u.w);
            }
        } else {
#pragma unroll
            for (int i = 0; i < 32; i++) tmp[i] = 0;
        }
        short* dst = (which ? &sH[r][c0] : &sA[r][c0]);
#pragma unroll
        for (int i = 0; i < 4; i++)
            *(bf16x8*)(dst + i * 8) = *(bf16x8*)&tmp[i * 8];
    }
    __syncthreads();

    int wid = tid >> 6, lane = tid & 63;
    int jw = wid * 32;
    int lr = lane & 15, lg = lane >> 4;

    f32x4 acc[6][4][2] = {};

    for (int k0 = 0; k0 < H; k0 += 32) {
        bf16x8 fa[4], fh[4];
#pragma unroll
        for (int rh = 0; rh < 4; rh++) {
            fa[rh] = *(const bf16x8*)&sA[rh * 16 + lr][k0 + lg * 8];
            fh[rh] = *(const bf16x8*)&sH[rh * 16 + lr][k0 + lg * 8];
        }
#pragma unroll
        for (int g = 0; g < 6; g++) {
            const short* wb = ((g < 3) ? wihb : whhb) + (size_t)(g % 3) * H * H;
            bf16x8 fb[2];
#pragma unroll
            for (int ch = 0; ch < 2; ch++) {
                int c = jw + ch * 16 + lr;
                fb[ch] = *(const bf16x8*)(wb + (size_t)c * H + k0 + lg * 8);
            }
#pragma unroll
            for (int rh = 0; rh < 4; rh++)
#pragma unroll
                for (int ch = 0; ch < 2; ch++)
                    acc[g][rh][ch] = __builtin_amdgcn_mfma_f32_16x16x32_bf16(
                        (g < 3) ? fa[rh] : fh[rh], fb[ch], acc[g][rh][ch], 0, 0, 0);
        }
    }

#pragma unroll
    for (int rh = 0; rh < 4; rh++) {
#pragma unroll
        for (int reg = 0; reg < 4; reg++) {
            int row = rh * 16 + lg * 4 + reg;
            int n = n0 + row;
            if (n >= NN) continue;
#pragma unroll
            for (int ch = 0; ch < 2; ch++) {
                int jj = jw + ch * 16 + lr;
                float ir  = acc[0][rh][ch][reg] + bih[jj];
                float iz  = acc[1][rh][ch][reg] + bih[H + jj];
                float in_ = acc[2][rh][ch][reg] + bih[2 * H + jj];
                float hr  = acc[3][rh][ch][reg] + bhh[jj];
                float hz  = acc[4][rh][ch][reg] + bhh[H + jj];
                float hn  = acc[5][rh][ch][reg] + bhh[2 * H + jj];
                float r = 1.f / (1.f + expf(-(ir + hr)));
                float z = 1.f / (1.f + expf(-(iz + hz)));
                float nv = tanhf(in_ + r * hn);
                float ho = bf2f(sH[row][jj]);
                hnext[(size_t)n * H + jj] = (1.f - z) * nv + z * ho;
            }
        }
    }
}

extern "C" void kernel_launch(void* const* d_in, const int* in_sizes, int n_in,
                              void* d_out, int out_size, void* d_ws, size_t ws_size,
                              hipStream_t stream) {
    const int*   x     = (const int*)d_in[0];
    const int*   ei    = (const int*)d_in[1];
    const int*   etype = (const int*)d_in[2];
    const float* emb   = (const float*)d_in[3];
    const float* Wm    = (const float*)d_in[4];
    const float* bm    = (const float*)d_in[5];
    const float* wih   = (const float*)d_in[6];
    const float* whh   = (const float*)d_in[7];
    const float* bih   = (const float*)d_in[8];
    const float* bhh   = (const float*)d_in[9];

    float* out = (float*)d_out;

    float* ws_h = (float*)d_ws;
    float* aggr = ws_h + (size_t)NN * H;
    short* wihb = (short*)(aggr + (size_t)NN * H);
    short* whhb = wihb + 3 * H * H;
    short* WmT  = whhb + 3 * H * H;
    int* hist_tb = (int*)(WmT + NT * H * H);
    int* off_tb  = hist_tb + NT * NB;
    int* pstart  = off_tb + NT * NB;
    int* perm    = pstart + 16;

    k_embed<<<2048, 256, 0, stream>>>(x, emb, ws_h);
    k_prep<<<720, 256, 0, stream>>>(wih, whh, Wm, wihb, whhb, WmT);

    k_hist<<<NB, CHUNK, 0, stream>>>(etype, hist_tb);
    k_scan<<<1, 64, 0, stream>>>(hist_tb, off_tb, pstart, perm);
    k_scatter<<<NB, CHUNK, 0, stream>>>(etype, off_tb, pstart, perm);

    const int MSG_BX = (NE + NT * 128 + 127) / 128;
    const int GRU_BX = (NN + 63) / 64;

    float* hcur = ws_h;
    float* hnxt = out;
    for (int s = 0; s < NSTEPS; s++) {
        hipMemsetAsync(aggr, 0, (size_t)NN * H * sizeof(float), stream);
        k_msg<<<MSG_BX, 512, 0, stream>>>(perm, pstart, ei, hcur, WmT, bm, aggr);
        k_gru<<<GRU_BX, 512, 0, stream>>>(aggr, hcur, hnxt, wihb, whhb, bih, bhh);
        float* tmp = hcur; hcur = hnxt; hnxt = tmp;
    }
}

// Round 7
// 3312.326 us; speedup vs baseline: 4.6074x; 1.1426x over previous
//
#include <hip/hip_runtime.h>
#include <math.h>

#define NN 100000
#define NE 300000
#define H 256
#define NT 8
#define NSTEPS 5
#define CHUNK 256
#define NB ((NE + CHUNK - 1) / CHUNK)
#define RS 264   // LDS row stride in shorts

typedef __attribute__((ext_vector_type(8))) short bf16x8;
typedef __attribute__((ext_vector_type(4))) float f32x4;

static __device__ __forceinline__ short f2bf(float f) {
    union { float f; unsigned u; } v; v.f = f;
    unsigned r = (v.u + 0x7FFFu + ((v.u >> 16) & 1u)) >> 16;
    return (short)r;
}
static __device__ __forceinline__ float bf2f(short s) {
    union { unsigned u; float f; } v; v.u = ((unsigned)(unsigned short)s) << 16;
    return v.f;
}

// ---------------- embedding gather: h0 = emb[x] (fp32) ----------------
__global__ void k_embed(const int* __restrict__ x, const float* __restrict__ emb,
                        float* __restrict__ h) {
    int total = NN * (H / 4);
    for (int idx = blockIdx.x * blockDim.x + threadIdx.x; idx < total;
         idx += gridDim.x * blockDim.x) {
        int node = idx >> 6;
        int j4   = idx & 63;
        reinterpret_cast<float4*>(h)[idx] =
            reinterpret_cast<const float4*>(emb + (size_t)x[node] * H)[j4];
    }
}

// ---------------- weight prep: bf16 copies (W_msg transposed) ----------------
__global__ void k_prep(const float* __restrict__ wih, const float* __restrict__ whh,
                       const float* __restrict__ Wm,
                       short* __restrict__ wihb, short* __restrict__ whhb,
                       short* __restrict__ WmT) {
    int n1 = 3 * H * H;
    int n2 = NT * H * H;
    for (int i = blockIdx.x * blockDim.x + threadIdx.x; i < n1 + n2;
         i += gridDim.x * blockDim.x) {
        if (i < n1) {
            wihb[i] = f2bf(wih[i]);
            whhb[i] = f2bf(whh[i]);
        } else {
            int idx = i - n1;
            int t = idx >> 16, rem = idx & 65535;
            int j = rem >> 8, k = rem & 255;
            WmT[idx] = f2bf(Wm[(size_t)t * H * H + (size_t)k * H + j]);
        }
    }
}

// ---------------- stable counting sort of edges by type ----------------
__global__ void k_hist(const int* __restrict__ etype, int* __restrict__ hist_tb) {
    __shared__ int lh[NT];
    int b = blockIdx.x;
    if (threadIdx.x < NT) lh[threadIdx.x] = 0;
    __syncthreads();
    int e = b * CHUNK + threadIdx.x;
    if (e < NE) atomicAdd(&lh[etype[e]], 1);
    __syncthreads();
    if (threadIdx.x < NT) hist_tb[threadIdx.x * NB + b] = lh[threadIdx.x];
}

__global__ void k_scan(const int* __restrict__ hist_tb, int* __restrict__ off_tb,
                       int* __restrict__ pstart, int* __restrict__ perm) {
    __shared__ int total[NT];
    int t = threadIdx.x;
    if (t < NT) {
        int run = 0;
        for (int b = 0; b < NB; b++) {
            off_tb[t * NB + b] = run;
            run += hist_tb[t * NB + b];
        }
        total[t] = run;
    }
    __syncthreads();
    if (t == 0) {
        int p = 0;
        for (int tt = 0; tt < NT; tt++) {
            pstart[tt] = p;
            int padded = (total[tt] + 127) / 128 * 128;
            for (int q = total[tt]; q < padded; q++) perm[p + q] = -1;
            p += padded;
        }
        pstart[NT] = p;
    }
}

__global__ void k_scatter(const int* __restrict__ etype, const int* __restrict__ off_tb,
                          const int* __restrict__ pstart, int* __restrict__ perm) {
    __shared__ int st[CHUNK];
    int b = blockIdx.x;
    int e = b * CHUNK + threadIdx.x;
    st[threadIdx.x] = (e < NE) ? etype[e] : -1;
    __syncthreads();
    if (e < NE) {
        int t = st[threadIdx.x];
        int r = 0;
        for (int i = 0; i < threadIdx.x; i++) r += (st[i] == t);
        perm[pstart[t] + off_tb[t * NB + b] + r] = e;
    }
}

// ---------------- message GEMM (MFMA): aggr[dst] += h[src] @ W[t] + b[t] ----
// Block: 128 edges x 256 cols, 512 threads (8 waves x 32-col slice).
__global__ __launch_bounds__(512) void k_msg(
    const int* __restrict__ perm, const int* __restrict__ pstart,
    const int* __restrict__ ei, const float* __restrict__ hcur,
    const short* __restrict__ WmT, const float* __restrict__ bm,
    float* __restrict__ aggr) {
    int Epad = pstart[NT];
    int e0 = blockIdx.x * 128;
    if (e0 >= Epad) return;
    int t = 0;
    while (t < NT - 1 && e0 >= pstart[t + 1]) t++;

    __shared__ short sA[128][RS];
    __shared__ int se[128], de[128];

    int tid = threadIdx.x;
    if (tid < 128) {
        int eid = perm[e0 + tid];
        se[tid] = (eid >= 0) ? ei[eid] : -1;
        de[tid] = (eid >= 0) ? ei[NE + eid] : 0;
    }
    __syncthreads();

    // stage h[src] tile -> LDS bf16 (float4-vectorized)
    for (int task = tid; task < 1024; task += 512) {
        int r = task >> 3, c0 = (task & 7) * 32;
        int s = se[r];
        short tmp[32];
        if (s >= 0) {
            const float4* p4 = reinterpret_cast<const float4*>(hcur + (size_t)s * H + c0);
#pragma unroll
            for (int i = 0; i < 8; i++) {
                float4 u = p4[i];
                tmp[i * 4 + 0] = f2bf(u.x); tmp[i * 4 + 1] = f2bf(u.y);
                tmp[i * 4 + 2] = f2bf(u.z); tmp[i * 4 + 3] = f2bf(u.w);
            }
        } else {
#pragma unroll
            for (int i = 0; i < 32; i++) tmp[i] = 0;
        }
#pragma unroll
        for (int i = 0; i < 4; i++)
            *(bf16x8*)&sA[r][c0 + i * 8] = *(bf16x8*)&tmp[i * 8];
    }
    __syncthreads();

    int wid = tid >> 6, lane = tid & 63;
    int jw = wid * 32;
    int lr = lane & 15, lg = lane >> 4;

    const short* wt = WmT + (size_t)t * H * H;   // [j][k]
    f32x4 acc[8][2] = {};

    for (int k0 = 0; k0 < H; k0 += 32) {
        bf16x8 fb[2];
#pragma unroll
        for (int ch = 0; ch < 2; ch++) {
            int c = jw + ch * 16 + lr;
            fb[ch] = *(const bf16x8*)(wt + (size_t)c * H + k0 + lg * 8);
        }
#pragma unroll
        for (int rh = 0; rh < 8; rh++) {
            bf16x8 fa = *(const bf16x8*)&sA[rh * 16 + lr][k0 + lg * 8];
#pragma unroll
            for (int ch = 0; ch < 2; ch++)
                acc[rh][ch] = __builtin_amdgcn_mfma_f32_16x16x32_bf16(
                    fa, fb[ch], acc[rh][ch], 0, 0, 0);
        }
    }

#pragma unroll
    for (int rh = 0; rh < 8; rh++) {
#pragma unroll
        for (int reg = 0; reg < 4; reg++) {
            int row = rh * 16 + lg * 4 + reg;
            int s = se[row];
            if (s < 0) continue;
            int d = de[row];
#pragma unroll
            for (int ch = 0; ch < 2; ch++) {
                int jj = jw + ch * 16 + lr;
                atomicAdd(&aggr[(size_t)d * H + jj], acc[rh][ch][reg] + bm[t * H + jj]);
            }
        }
    }
}

// ---------------- fused GRU (MFMA): h' = GRUCell(aggr, h) ----------------
// Block: 64 nodes x 256 cols x 6 gates, 512 threads (8 waves x 32-col slice).
// acc[6][4][2] f32x4 = 192 f32/thread. Rounds 4-6 evidence: default allocator
// targets 128 VGPRs for 512-thr blocks and __launch_bounds__ 2nd arg (either
// semantics) does NOT raise it -> acc spills -> 553 MB/dispatch scratch writes.
// Direct knob: amdgpu-waves-per-eu=2,2 -> budget 512-reg file / 2 waves = 256.
__global__ __launch_bounds__(512)
__attribute__((amdgpu_waves_per_eu(2, 2))) void k_gru(
    const float* __restrict__ aggr, const float* __restrict__ hcur,
    float* __restrict__ hnext,
    const short* __restrict__ wihb, const short* __restrict__ whhb,
    const float* __restrict__ bih, const float* __restrict__ bhh) {
    int n0 = blockIdx.x * 64;
    int tid = threadIdx.x;

    __shared__ short sA[64][RS];
    __shared__ short sH[64][RS];

    // stage: 1024 tasks = 2 mats x 64 rows x 8 col-chunks(32), float4-vectorized
    for (int task = tid; task < 1024; task += 512) {
        int which = task >> 9;
        int t2 = task & 511;
        int r = t2 >> 3, c0 = (t2 & 7) * 32;
        int n = n0 + r;
        short tmp[32];
        if (n < NN) {
            const float4* p4 = reinterpret_cast<const float4*>(
                (which ? hcur : aggr) + (size_t)n * H + c0);
#pragma unroll
            for (int i = 0; i < 8; i++) {
                float4 u = p4[i];
                tmp[i * 4 + 0] = f2bf(u.x); tmp[i * 4 + 1] = f2bf(u.y);
                tmp[i * 4 + 2] = f2bf(u.z); tmp[i * 4 + 3] = f2bf(u.w);
            }
        } else {
#pragma unroll
            for (int i = 0; i < 32; i++) tmp[i] = 0;
        }
        short* dst = (which ? &sH[r][c0] : &sA[r][c0]);
#pragma unroll
        for (int i = 0; i < 4; i++)
            *(bf16x8*)(dst + i * 8) = *(bf16x8*)&tmp[i * 8];
    }
    __syncthreads();

    int wid = tid >> 6, lane = tid & 63;
    int jw = wid * 32;
    int lr = lane & 15, lg = lane >> 4;

    f32x4 acc[6][4][2] = {};

    for (int k0 = 0; k0 < H; k0 += 32) {
        bf16x8 fa[4], fh[4];
#pragma unroll
        for (int rh = 0; rh < 4; rh++) {
            fa[rh] = *(const bf16x8*)&sA[rh * 16 + lr][k0 + lg * 8];
            fh[rh] = *(const bf16x8*)&sH[rh * 16 + lr][k0 + lg * 8];
        }
#pragma unroll
        for (int g = 0; g < 6; g++) {
            const short* wb = ((g < 3) ? wihb : whhb) + (size_t)(g % 3) * H * H;
            bf16x8 fb[2];
#pragma unroll
            for (int ch = 0; ch < 2; ch++) {
                int c = jw + ch * 16 + lr;
                fb[ch] = *(const bf16x8*)(wb + (size_t)c * H + k0 + lg * 8);
            }
#pragma unroll
            for (int rh = 0; rh < 4; rh++)
#pragma unroll
                for (int ch = 0; ch < 2; ch++)
                    acc[g][rh][ch] = __builtin_amdgcn_mfma_f32_16x16x32_bf16(
                        (g < 3) ? fa[rh] : fh[rh], fb[ch], acc[g][rh][ch], 0, 0, 0);
        }
    }

#pragma unroll
    for (int rh = 0; rh < 4; rh++) {
#pragma unroll
        for (int reg = 0; reg < 4; reg++) {
            int row = rh * 16 + lg * 4 + reg;
            int n = n0 + row;
            if (n >= NN) continue;
#pragma unroll
            for (int ch = 0; ch < 2; ch++) {
                int jj = jw + ch * 16 + lr;
                float ir  = acc[0][rh][ch][reg] + bih[jj];
                float iz  = acc[1][rh][ch][reg] + bih[H + jj];
                float in_ = acc[2][rh][ch][reg] + bih[2 * H + jj];
                float hr  = acc[3][rh][ch][reg] + bhh[jj];
                float hz  = acc[4][rh][ch][reg] + bhh[H + jj];
                float hn  = acc[5][rh][ch][reg] + bhh[2 * H + jj];
                float r = 1.f / (1.f + expf(-(ir + hr)));
                float z = 1.f / (1.f + expf(-(iz + hz)));
                float nv = tanhf(in_ + r * hn);
                float ho = bf2f(sH[row][jj]);
                hnext[(size_t)n * H + jj] = (1.f - z) * nv + z * ho;
            }
        }
    }
}

extern "C" void kernel_launch(void* const* d_in, const int* in_sizes, int n_in,
                              void* d_out, int out_size, void* d_ws, size_t ws_size,
                              hipStream_t stream) {
    const int*   x     = (const int*)d_in[0];
    const int*   ei    = (const int*)d_in[1];
    const int*   etype = (const int*)d_in[2];
    const float* emb   = (const float*)d_in[3];
    const float* Wm    = (const float*)d_in[4];
    const float* bm    = (const float*)d_in[5];
    const float* wih   = (const float*)d_in[6];
    const float* whh   = (const float*)d_in[7];
    const float* bih   = (const float*)d_in[8];
    const float* bhh   = (const float*)d_in[9];

    float* out = (float*)d_out;

    float* ws_h = (float*)d_ws;
    float* aggr = ws_h + (size_t)NN * H;
    short* wihb = (short*)(aggr + (size_t)NN * H);
    short* whhb = wihb + 3 * H * H;
    short* WmT  = whhb + 3 * H * H;
    int* hist_tb = (int*)(WmT + NT * H * H);
    int* off_tb  = hist_tb + NT * NB;
    int* pstart  = off_tb + NT * NB;
    int* perm    = pstart + 16;

    k_embed<<<2048, 256, 0, stream>>>(x, emb, ws_h);
    k_prep<<<720, 256, 0, stream>>>(wih, whh, Wm, wihb, whhb, WmT);

    k_hist<<<NB, CHUNK, 0, stream>>>(etype, hist_tb);
    k_scan<<<1, 64, 0, stream>>>(hist_tb, off_tb, pstart, perm);
    k_scatter<<<NB, CHUNK, 0, stream>>>(etype, off_tb, pstart, perm);

    const int MSG_BX = (NE + NT * 128 + 127) / 128;
    const int GRU_BX = (NN + 63) / 64;

    float* hcur = ws_h;
    float* hnxt = out;
    for (int s = 0; s < NSTEPS; s++) {
        hipMemsetAsync(aggr, 0, (size_t)NN * H * sizeof(float), stream);
        k_msg<<<MSG_BX, 512, 0, stream>>>(perm, pstart, ei, hcur, WmT, bm, aggr);
        k_gru<<<GRU_BX, 512, 0, stream>>>(aggr, hcur, hnxt, wihb, whhb, bih, bhh);
        float* tmp = hcur; hcur = hnxt; hnxt = tmp;
    }
}

// Round 8
// 3096.603 us; speedup vs baseline: 4.9284x; 1.0697x over previous
//
#include <hip/hip_runtime.h>
#include <math.h>

#define NN 100000
#define NE 300000
#define H 256
#define NT 8
#define NSTEPS 5
#define CHUNK 256
#define NB ((NE + CHUNK - 1) / CHUNK)
#define RS 264   // LDS row stride in shorts

typedef __attribute__((ext_vector_type(8))) short bf16x8;
typedef __attribute__((ext_vector_type(4))) float f32x4;

static __device__ __forceinline__ short f2bf(float f) {
    union { float f; unsigned u; } v; v.f = f;
    unsigned r = (v.u + 0x7FFFu + ((v.u >> 16) & 1u)) >> 16;
    return (short)r;
}
static __device__ __forceinline__ float bf2f(short s) {
    union { unsigned u; float f; } v; v.u = ((unsigned)(unsigned short)s) << 16;
    return v.f;
}

// ---------------- embedding gather: h0 = emb[x] (fp32) ----------------
__global__ void k_embed(const int* __restrict__ x, const float* __restrict__ emb,
                        float* __restrict__ h) {
    int total = NN * (H / 4);
    for (int idx = blockIdx.x * blockDim.x + threadIdx.x; idx < total;
         idx += gridDim.x * blockDim.x) {
        int node = idx >> 6;
        int j4   = idx & 63;
        reinterpret_cast<float4*>(h)[idx] =
            reinterpret_cast<const float4*>(emb + (size_t)x[node] * H)[j4];
    }
}

// ---------------- weight prep: bf16 copies (W_msg transposed) ----------------
__global__ void k_prep(const float* __restrict__ wih, const float* __restrict__ whh,
                       const float* __restrict__ Wm,
                       short* __restrict__ wihb, short* __restrict__ whhb,
                       short* __restrict__ WmT) {
    int n1 = 3 * H * H;
    int n2 = NT * H * H;
    for (int i = blockIdx.x * blockDim.x + threadIdx.x; i < n1 + n2;
         i += gridDim.x * blockDim.x) {
        if (i < n1) {
            wihb[i] = f2bf(wih[i]);
            whhb[i] = f2bf(whh[i]);
        } else {
            int idx = i - n1;
            int t = idx >> 16, rem = idx & 65535;
            int j = rem >> 8, k = rem & 255;
            WmT[idx] = f2bf(Wm[(size_t)t * H * H + (size_t)k * H + j]);
        }
    }
}

// ---------------- stable counting sort of edges by type ----------------
__global__ void k_hist(const int* __restrict__ etype, int* __restrict__ hist_tb) {
    __shared__ int lh[NT];
    int b = blockIdx.x;
    if (threadIdx.x < NT) lh[threadIdx.x] = 0;
    __syncthreads();
    int e = b * CHUNK + threadIdx.x;
    if (e < NE) atomicAdd(&lh[etype[e]], 1);
    __syncthreads();
    if (threadIdx.x < NT) hist_tb[threadIdx.x * NB + b] = lh[threadIdx.x];
}

__global__ void k_scan(const int* __restrict__ hist_tb, int* __restrict__ off_tb,
                       int* __restrict__ pstart, int* __restrict__ perm) {
    __shared__ int total[NT];
    int t = threadIdx.x;
    if (t < NT) {
        int run = 0;
        for (int b = 0; b < NB; b++) {
            off_tb[t * NB + b] = run;
            run += hist_tb[t * NB + b];
        }
        total[t] = run;
    }
    __syncthreads();
    if (t == 0) {
        int p = 0;
        for (int tt = 0; tt < NT; tt++) {
            pstart[tt] = p;
            int padded = (total[tt] + 127) / 128 * 128;
            for (int q = total[tt]; q < padded; q++) perm[p + q] = -1;
            p += padded;
        }
        pstart[NT] = p;
    }
}

__global__ void k_scatter(const int* __restrict__ etype, const int* __restrict__ off_tb,
                          const int* __restrict__ pstart, int* __restrict__ perm) {
    __shared__ int st[CHUNK];
    int b = blockIdx.x;
    int e = b * CHUNK + threadIdx.x;
    st[threadIdx.x] = (e < NE) ? etype[e] : -1;
    __syncthreads();
    if (e < NE) {
        int t = st[threadIdx.x];
        int r = 0;
        for (int i = 0; i < threadIdx.x; i++) r += (st[i] == t);
        perm[pstart[t] + off_tb[t * NB + b] + r] = e;
    }
}

// ---------------- message GEMM (MFMA): aggr[dst] += h[src] @ W[t] + b[t] ----
// Block: 128 edges x 256 cols, 512 threads (8 waves x 32-col slice).
__global__ __launch_bounds__(512) void k_msg(
    const int* __restrict__ perm, const int* __restrict__ pstart,
    const int* __restrict__ ei, const float* __restrict__ hcur,
    const short* __restrict__ WmT, const float* __restrict__ bm,
    float* __restrict__ aggr) {
    int Epad = pstart[NT];
    int e0 = blockIdx.x * 128;
    if (e0 >= Epad) return;
    int t = 0;
    while (t < NT - 1 && e0 >= pstart[t + 1]) t++;

    __shared__ short sA[128][RS];
    __shared__ int se[128], de[128];

    int tid = threadIdx.x;
    if (tid < 128) {
        int eid = perm[e0 + tid];
        se[tid] = (eid >= 0) ? ei[eid] : -1;
        de[tid] = (eid >= 0) ? ei[NE + eid] : 0;
    }
    __syncthreads();

    // stage h[src] tile -> LDS bf16 (float4-vectorized)
    for (int task = tid; task < 1024; task += 512) {
        int r = task >> 3, c0 = (task & 7) * 32;
        int s = se[r];
        short tmp[32];
        if (s >= 0) {
            const float4* p4 = reinterpret_cast<const float4*>(hcur + (size_t)s * H + c0);
#pragma unroll
            for (int i = 0; i < 8; i++) {
                float4 u = p4[i];
                tmp[i * 4 + 0] = f2bf(u.x); tmp[i * 4 + 1] = f2bf(u.y);
                tmp[i * 4 + 2] = f2bf(u.z); tmp[i * 4 + 3] = f2bf(u.w);
            }
        } else {
#pragma unroll
            for (int i = 0; i < 32; i++) tmp[i] = 0;
        }
#pragma unroll
        for (int i = 0; i < 4; i++)
            *(bf16x8*)&sA[r][c0 + i * 8] = *(bf16x8*)&tmp[i * 8];
    }
    __syncthreads();

    int wid = tid >> 6, lane = tid & 63;
    int jw = wid * 32;
    int lr = lane & 15, lg = lane >> 4;

    const short* wt = WmT + (size_t)t * H * H;   // [j][k]
    f32x4 acc[8][2] = {};

    for (int k0 = 0; k0 < H; k0 += 32) {
        bf16x8 fb[2];
#pragma unroll
        for (int ch = 0; ch < 2; ch++) {
            int c = jw + ch * 16 + lr;
            fb[ch] = *(const bf16x8*)(wt + (size_t)c * H + k0 + lg * 8);
        }
#pragma unroll
        for (int rh = 0; rh < 8; rh++) {
            bf16x8 fa = *(const bf16x8*)&sA[rh * 16 + lr][k0 + lg * 8];
#pragma unroll
            for (int ch = 0; ch < 2; ch++)
                acc[rh][ch] = __builtin_amdgcn_mfma_f32_16x16x32_bf16(
                    fa, fb[ch], acc[rh][ch], 0, 0, 0);
        }
    }

#pragma unroll
    for (int rh = 0; rh < 8; rh++) {
#pragma unroll
        for (int reg = 0; reg < 4; reg++) {
            int row = rh * 16 + lg * 4 + reg;
            int s = se[row];
            if (s < 0) continue;
            int d = de[row];
#pragma unroll
            for (int ch = 0; ch < 2; ch++) {
                int jj = jw + ch * 16 + lr;
                atomicAdd(&aggr[(size_t)d * H + jj], acc[rh][ch][reg] + bm[t * H + jj]);
            }
        }
    }
}

// ---------------- fused GRU (MFMA): h' = GRUCell(aggr, h) ----------------
// Block: 64 nodes x 256 cols, 512 threads (8 waves x 32-col slice).
// Accumulator algebra: r and z gates need only (i_*+h_*), so ih- and hh-GEMMs
// CHAIN into one accumulator each. acc matrices: {r, z, i_n, h_n} = 4
// -> 128 f32/thread (one AGPR bank), fragments+addressing fit in arch VGPRs.
__global__ __launch_bounds__(512)
__attribute__((amdgpu_waves_per_eu(2, 2))) void k_gru(
    const float* __restrict__ aggr, const float* __restrict__ hcur,
    float* __restrict__ hnext,
    const short* __restrict__ wihb, const short* __restrict__ whhb,
    const float* __restrict__ bih, const float* __restrict__ bhh) {
    int n0 = blockIdx.x * 64;
    int tid = threadIdx.x;

    __shared__ short sA[64][RS];
    __shared__ short sH[64][RS];

    // stage: 1024 tasks = 2 mats x 64 rows x 8 col-chunks(32), float4-vectorized
    for (int task = tid; task < 1024; task += 512) {
        int which = task >> 9;
        int t2 = task & 511;
        int r = t2 >> 3, c0 = (t2 & 7) * 32;
        int n = n0 + r;
        short tmp[32];
        if (n < NN) {
            const float4* p4 = reinterpret_cast<const float4*>(
                (which ? hcur : aggr) + (size_t)n * H + c0);
#pragma unroll
            for (int i = 0; i < 8; i++) {
                float4 u = p4[i];
                tmp[i * 4 + 0] = f2bf(u.x); tmp[i * 4 + 1] = f2bf(u.y);
                tmp[i * 4 + 2] = f2bf(u.z); tmp[i * 4 + 3] = f2bf(u.w);
            }
        } else {
#pragma unroll
            for (int i = 0; i < 32; i++) tmp[i] = 0;
        }
        short* dst = (which ? &sH[r][c0] : &sA[r][c0]);
#pragma unroll
        for (int i = 0; i < 4; i++)
            *(bf16x8*)(dst + i * 8) = *(bf16x8*)&tmp[i * 8];
    }
    __syncthreads();

    int wid = tid >> 6, lane = tid & 63;
    int jw = wid * 32;
    int lr = lane & 15, lg = lane >> 4;

    // acc[0]=r (i_r+h_r), acc[1]=z (i_z+h_z), acc[2]=i_n, acc[3]=h_n
    f32x4 acc[4][4][2] = {};

    for (int k0 = 0; k0 < H; k0 += 32) {
        bf16x8 fa[4], fh[4];
#pragma unroll
        for (int rh = 0; rh < 4; rh++) {
            fa[rh] = *(const bf16x8*)&sA[rh * 16 + lr][k0 + lg * 8];
            fh[rh] = *(const bf16x8*)&sH[rh * 16 + lr][k0 + lg * 8];
        }
        // g: 0=ih_r 1=hh_r 2=ih_z 3=hh_z 4=ih_n 5=hh_n
#pragma unroll
        for (int g = 0; g < 6; g++) {
            const short* wb = ((g & 1) ? whhb : wihb) + (size_t)(g >> 1) * H * H;
            int di = (g < 4) ? (g >> 1) : (g - 2);   // 0,0,1,1,2,3
            bf16x8 fb[2];
#pragma unroll
            for (int ch = 0; ch < 2; ch++) {
                int c = jw + ch * 16 + lr;
                fb[ch] = *(const bf16x8*)(wb + (size_t)c * H + k0 + lg * 8);
            }
#pragma unroll
            for (int rh = 0; rh < 4; rh++)
#pragma unroll
                for (int ch = 0; ch < 2; ch++)
                    acc[di][rh][ch] = __builtin_amdgcn_mfma_f32_16x16x32_bf16(
                        (g & 1) ? fh[rh] : fa[rh], fb[ch], acc[di][rh][ch], 0, 0, 0);
        }
    }

#pragma unroll
    for (int rh = 0; rh < 4; rh++) {
#pragma unroll
        for (int reg = 0; reg < 4; reg++) {
            int row = rh * 16 + lg * 4 + reg;
            int n = n0 + row;
            if (n >= NN) continue;
#pragma unroll
            for (int ch = 0; ch < 2; ch++) {
                int jj = jw + ch * 16 + lr;
                float rr = acc[0][rh][ch][reg] + bih[jj] + bhh[jj];
                float zz = acc[1][rh][ch][reg] + bih[H + jj] + bhh[H + jj];
                float nn = acc[2][rh][ch][reg] + bih[2 * H + jj];
                float hn = acc[3][rh][ch][reg] + bhh[2 * H + jj];
                float r = 1.f / (1.f + expf(-rr));
                float z = 1.f / (1.f + expf(-zz));
                float nv = tanhf(nn + r * hn);
                float ho = bf2f(sH[row][jj]);
                hnext[(size_t)n * H + jj] = (1.f - z) * nv + z * ho;
            }
        }
    }
}

extern "C" void kernel_launch(void* const* d_in, const int* in_sizes, int n_in,
                              void* d_out, int out_size, void* d_ws, size_t ws_size,
                              hipStream_t stream) {
    const int*   x     = (const int*)d_in[0];
    const int*   ei    = (const int*)d_in[1];
    const int*   etype = (const int*)d_in[2];
    const float* emb   = (const float*)d_in[3];
    const float* Wm    = (const float*)d_in[4];
    const float* bm    = (const float*)d_in[5];
    const float* wih   = (const float*)d_in[6];
    const float* whh   = (const float*)d_in[7];
    const float* bih   = (const float*)d_in[8];
    const float* bhh   = (const float*)d_in[9];

    float* out = (float*)d_out;

    float* ws_h = (float*)d_ws;
    float* aggr = ws_h + (size_t)NN * H;
    short* wihb = (short*)(aggr + (size_t)NN * H);
    short* whhb = wihb + 3 * H * H;
    short* WmT  = whhb + 3 * H * H;
    int* hist_tb = (int*)(WmT + NT * H * H);
    int* off_tb  = hist_tb + NT * NB;
    int* pstart  = off_tb + NT * NB;
    int* perm    = pstart + 16;

    k_embed<<<2048, 256, 0, stream>>>(x, emb, ws_h);
    k_prep<<<720, 256, 0, stream>>>(wih, whh, Wm, wihb, whhb, WmT);

    k_hist<<<NB, CHUNK, 0, stream>>>(etype, hist_tb);
    k_scan<<<1, 64, 0, stream>>>(hist_tb, off_tb, pstart, perm);
    k_scatter<<<NB, CHUNK, 0, stream>>>(etype, off_tb, pstart, perm);

    const int MSG_BX = (NE + NT * 128 + 127) / 128;
    const int GRU_BX = (NN + 63) / 64;

    float* hcur = ws_h;
    float* hnxt = out;
    for (int s = 0; s < NSTEPS; s++) {
        hipMemsetAsync(aggr, 0, (size_t)NN * H * sizeof(float), stream);
        k_msg<<<MSG_BX, 512, 0, stream>>>(perm, pstart, ei, hcur, WmT, bm, aggr);
        k_gru<<<GRU_BX, 512, 0, stream>>>(aggr, hcur, hnxt, wihb, whhb, bih, bhh);
        float* tmp = hcur; hcur = hnxt; hnxt = tmp;
    }
}